// Round 2
// baseline (1983.254 us; speedup 1.0000x reference)
//
#include <hip/hip_runtime.h>
#include <hip/hip_bf16.h>
#include <stdint.h>

using u16 = unsigned short;
typedef float floatx4 __attribute__((ext_vector_type(4)));
typedef __bf16 bfv8 __attribute__((ext_vector_type(8)));

#define AS1 __attribute__((address_space(1)))
#define AS3 __attribute__((address_space(3)))

__device__ __forceinline__ u16 f2bf_bits(float f) {
    __hip_bfloat16 h = __float2bfloat16(f);
    u16 u;
    __builtin_memcpy(&u, &h, 2);
    return u;
}
__device__ __forceinline__ float bf_bits2f(u16 u) {
    __hip_bfloat16 h;
    __builtin_memcpy(&h, &u, 2);
    return __bfloat162float(h);
}
__device__ __forceinline__ void gload_lds16(const void* g, void* l) {
    __builtin_amdgcn_global_load_lds((AS1 void*)(uintptr_t)g, (AS3 void*)l, 16, 0, 0);
}

// ---------------- cast fp32 -> bf16, 4 elems/thread ----------------
__global__ void cast_bf16_kernel(const float* __restrict__ in, u16* __restrict__ out, int n4) {
    int i = blockIdx.x * blockDim.x + threadIdx.x;
    if (i >= n4) return;
    float4 v = ((const float4*)in)[i];
    ushort4 o;
    o.x = f2bf_bits(v.x); o.y = f2bf_bits(v.y); o.z = f2bf_bits(v.z); o.w = f2bf_bits(v.w);
    ((ushort4*)out)[i] = o;
}

// ---------------- cast fp32 -> bf16 AND zero the fp32 source (self-cleaning split-K target) ----------------
__global__ void cast_zero_kernel(float* __restrict__ in, u16* __restrict__ out, int n4) {
    int i = blockIdx.x * blockDim.x + threadIdx.x;
    if (i >= n4) return;
    float4 v = ((float4*)in)[i];
    ushort4 o;
    o.x = f2bf_bits(v.x); o.y = f2bf_bits(v.y); o.z = f2bf_bits(v.z); o.w = f2bf_bits(v.w);
    ((ushort4*)out)[i] = o;
    ((float4*)in)[i] = make_float4(0.f, 0.f, 0.f, 0.f);
}

// ---------------- transpose+cast fp32 [z][R][C] -> bf16 [z][C][R] ----------------
__global__ void transpose_cast_kernel(const float* __restrict__ src, u16* __restrict__ dst,
                                      int R, int C, long sSrc, long sDst) {
    __shared__ float tile[32][33];
    const float* s = src + (long)blockIdx.z * sSrc;
    u16* d = dst + (long)blockIdx.z * sDst;
    int c0 = blockIdx.x * 32, r0 = blockIdx.y * 32;
    int tx = threadIdx.x, ty = threadIdx.y;
    #pragma unroll
    for (int i = 0; i < 4; i++)
        tile[ty + 8*i][tx] = s[(long)(r0 + ty + 8*i) * C + c0 + tx];
    __syncthreads();
    #pragma unroll
    for (int i = 0; i < 4; i++)
        d[(long)(c0 + ty + 8*i) * R + r0 + tx] = f2bf_bits(tile[tx][ty + 8*i]);
}

// ---------------- transpose V [4096][512]bf16 -> VT [16][128][1024]bf16 ----------------
__global__ void transpose_v_kernel(const u16* __restrict__ V, u16* __restrict__ VT) {
    __shared__ u16 tile[32][33];
    int z = blockIdx.z, b = z >> 2, h = z & 3;
    int s0 = blockIdx.x * 32, d0 = blockIdx.y * 32;
    int tx = threadIdx.x, ty = threadIdx.y;
    #pragma unroll
    for (int i = 0; i < 4; i++)
        tile[ty + 8*i][tx] = V[(long)(b*1024 + s0 + ty + 8*i) * 512 + h*128 + d0 + tx];
    __syncthreads();
    #pragma unroll
    for (int i = 0; i < 4; i++)
        VT[((long)z*128 + d0 + ty + 8*i) * 1024 + s0 + tx] = tile[tx][ty + 8*i];
}

// ---------------- pack bq/bk/bv -> PB[3][8][512] ----------------
__global__ void pack_bias_kernel(const float* __restrict__ bq, const float* __restrict__ bk,
                                 const float* __restrict__ bv, float* __restrict__ pb) {
    int i = blockIdx.x * 256 + threadIdx.x;  // 0..4095
    const float* s = blockIdx.y == 0 ? bq : (blockIdx.y == 1 ? bk : bv);
    pb[blockIdx.y * 4096 + i] = s[i];
}

// ---------------- router: logits + Scale-and-Fire routing weights ----------------
__global__ __launch_bounds__(512)
void router_kernel(const float* __restrict__ x, const float* __restrict__ gw,
                   const float* __restrict__ gb, float* __restrict__ rw,
                   float* __restrict__ logits_out) {
    int row = blockIdx.x;
    int w = threadIdx.x >> 6;     // expert 0..7
    int lane = threadIdx.x & 63;
    const float* xr = x + (long)row * 512;
    float sum = 0.f;
    #pragma unroll
    for (int i = 0; i < 8; i++) {
        int d = lane + 64 * i;
        sum += xr[d] * gw[d * 8 + w];
    }
    #pragma unroll
    for (int o = 32; o; o >>= 1) sum += __shfl_down(sum, o, 64);
    __shared__ float lg[8];
    if (lane == 0) lg[w] = sum + gb[w];
    __syncthreads();
    if (threadIdx.x == 0) {
        float l[8];
        #pragma unroll
        for (int e = 0; e < 8; e++) l[e] = lg[e];
        int i1 = 0;
        for (int e = 1; e < 8; e++) if (l[e] > l[i1]) i1 = e;
        int i2 = -1;
        for (int e = 0; e < 8; e++) { if (e == i1) continue; if (i2 < 0 || l[e] > l[i2]) i2 = e; }
        for (int e = 0; e < 8; e++) {
            float v = (e == i1 || e == i2) ? (l[e] > 0.f ? l[e] : 0.f) : 0.f;
            float r = 0.f, mem = v;
            #pragma unroll
            for (int lvl = 0; lvl < 4; lvl++) {
                float thr = 4.0f / (float)(1 << lvl);
                if (mem >= thr) { r += thr; mem -= thr; }
            }
            rw[(long)row * 8 + e] = r;
            logits_out[(long)row * 8 + e] = l[e];
        }
    }
}

// ---------------- GEMM: C[M,N] = A[M,K] @ Bt[N,K]^T (+bias)(relu)(alpha), m97 structure ----------------
// ATOMIC: split-K partial, fp32 atomicAdd epilogue; bias folded into ks==0 partial.
template<bool BIAS, bool RELU, bool SCALE, bool ATOMIC, typename OUT>
__global__ __launch_bounds__(256)
void gemm_kernel(const u16* __restrict__ A, int lda, long sAo, long sAi,
                 const u16* __restrict__ B, int ldb, long sBo, long sBi,
                 OUT* __restrict__ C, int ldc, long sCo, long sCi,
                 const float* __restrict__ bias, long sBiasO, long sBiasI,
                 int zdiv, int nks, float alpha, int K) {
    __shared__ __align__(16) u16 As[128 * 32];
    __shared__ __align__(16) u16 Bs[128 * 32];
    const int z = blockIdx.z;
    const int ks = z % nks;
    const int zz = z / nks;
    const int zo = zz / zdiv, zi = zz % zdiv;
    const int kc = K / nks;               // K-chunk for this split
    const int kbeg = ks * kc, kend = kbeg + kc;
    const u16* Ab = A + zo * sAo + zi * sAi + (long)blockIdx.y * 128 * lda;
    const u16* Bb = B + zo * sBo + zi * sBi + (long)blockIdx.x * 128 * ldb;

    const int tid = threadIdx.x;
    const int w = tid >> 6, lane = tid & 63;
    const int wy = w >> 1, wx = w & 1;
    const int lr = lane >> 2, lp = lane & 3;
    const int quad = lane >> 4, mrow = lane & 15;

    floatx4 acc[4][4];
    #pragma unroll
    for (int i = 0; i < 4; i++)
        #pragma unroll
        for (int j = 0; j < 4; j++)
            acc[i][j] = floatx4{0.f, 0.f, 0.f, 0.f};

    for (int k0 = kbeg; k0 < kend; k0 += 32) {
        #pragma unroll
        for (int j = 0; j < 2; j++) {
            const int s = w * 2 + j;
            const int r = s * 16 + lr;
            const int c = lp ^ ((r >> 1) & 3);   // XOR swizzle (16B chunks)
            gload_lds16(Ab + (long)r * lda + k0 + c * 8, As + s * 512);
            gload_lds16(Bb + (long)r * ldb + k0 + c * 8, Bs + s * 512);
        }
        __syncthreads();
        bfv8 af[4], bfr[4];
        #pragma unroll
        for (int mi = 0; mi < 4; mi++) {
            const int r = wy * 64 + mi * 16 + mrow;
            const int p = quad ^ ((r >> 1) & 3);
            af[mi] = *(const bfv8*)&As[r * 32 + p * 8];
        }
        #pragma unroll
        for (int ni = 0; ni < 4; ni++) {
            const int r = wx * 64 + ni * 16 + mrow;
            const int p = quad ^ ((r >> 1) & 3);
            bfr[ni] = *(const bfv8*)&Bs[r * 32 + p * 8];
        }
        #pragma unroll
        for (int mi = 0; mi < 4; mi++)
            #pragma unroll
            for (int ni = 0; ni < 4; ni++)
                acc[mi][ni] = __builtin_amdgcn_mfma_f32_16x16x32_bf16(af[mi], bfr[ni], acc[mi][ni], 0, 0, 0);
        __syncthreads();
    }

    OUT* Cb = C + zo * sCo + zi * sCi + (long)blockIdx.y * 128 * ldc + (long)blockIdx.x * 128;
    const float* biasb = BIAS ? (bias + zo * sBiasO + zi * sBiasI + (long)blockIdx.x * 128) : nullptr;
    #pragma unroll
    for (int ni = 0; ni < 4; ni++) {
        const int col = wx * 64 + ni * 16 + mrow;
        float bv = 0.f;
        if (BIAS && (!ATOMIC || ks == 0)) bv = biasb[col];
        #pragma unroll
        for (int mi = 0; mi < 4; mi++) {
            #pragma unroll
            for (int r = 0; r < 4; r++) {
                const int row = wy * 64 + mi * 16 + quad * 4 + r;
                float v = acc[mi][ni][r];
                if (SCALE) v *= alpha;
                if (BIAS && (!ATOMIC || ks == 0)) v += bv;
                if (RELU) v = fmaxf(v, 0.f);
                if constexpr (ATOMIC) {
                    atomicAdd(&((float*)Cb)[(long)row * ldc + col], v);
                } else if constexpr (sizeof(OUT) == 2) {
                    ((u16*)Cb)[(long)row * ldc + col] = f2bf_bits(v);
                } else {
                    ((float*)Cb)[(long)row * ldc + col] = v;
                }
            }
        }
    }
}

// ---------------- softmax over rows of 1024, in-place on bf16 ----------------
__global__ __launch_bounds__(256)
void softmax_kernel(u16* __restrict__ S) {
    long row = blockIdx.x;
    u16* p = S + row * 1024;
    int t = threadIdx.x, w = t >> 6, lane = t & 63;
    float v[4];
    float mx = -1e30f;
    #pragma unroll
    for (int i = 0; i < 4; i++) {
        v[i] = bf_bits2f(p[t + 256 * i]);
        mx = fmaxf(mx, v[i]);
    }
    #pragma unroll
    for (int o = 32; o; o >>= 1) mx = fmaxf(mx, __shfl_down(mx, o, 64));
    __shared__ float red[8];
    if (lane == 0) red[w] = mx;
    __syncthreads();
    mx = fmaxf(fmaxf(red[0], red[1]), fmaxf(red[2], red[3]));
    float sum = 0.f;
    #pragma unroll
    for (int i = 0; i < 4; i++) { v[i] = __expf(v[i] - mx); sum += v[i]; }
    #pragma unroll
    for (int o = 32; o; o >>= 1) sum += __shfl_down(sum, o, 64);
    if (lane == 0) red[4 + w] = sum;
    __syncthreads();
    float inv = 1.f / (red[4] + red[5] + red[6] + red[7]);
    #pragma unroll
    for (int i = 0; i < 4; i++) p[t + 256 * i] = f2bf_bits(v[i] * inv);
}

// ---------------- LN1: h = LN(x + t), write fp32 + bf16; zeroes t for next atomic use ----------------
__global__ __launch_bounds__(128)
void ln1_kernel(const float* __restrict__ x, float* __restrict__ t,
                const float* __restrict__ s, const float* __restrict__ b,
                float* __restrict__ hf, u16* __restrict__ hb) {
    long row = blockIdx.x;
    int tid = threadIdx.x, w = tid >> 6, lane = tid & 63;
    float4 xv = *(const float4*)(x + row * 512 + tid * 4);
    float4 tv = *(const float4*)(t + row * 512 + tid * 4);
    *(float4*)(t + row * 512 + tid * 4) = make_float4(0.f, 0.f, 0.f, 0.f);
    float v[4] = {xv.x + tv.x, xv.y + tv.y, xv.z + tv.z, xv.w + tv.w};
    float sum = v[0] + v[1] + v[2] + v[3];
    #pragma unroll
    for (int o = 32; o; o >>= 1) sum += __shfl_down(sum, o, 64);
    __shared__ float sh[4];
    if (lane == 0) sh[w] = sum;
    __syncthreads();
    float mu = (sh[0] + sh[1]) * (1.f / 512.f);
    float sq = 0.f;
    #pragma unroll
    for (int j = 0; j < 4; j++) { float d = v[j] - mu; sq += d * d; }
    #pragma unroll
    for (int o = 32; o; o >>= 1) sq += __shfl_down(sq, o, 64);
    if (lane == 0) sh[2 + w] = sq;
    __syncthreads();
    float inv = 1.f / sqrtf((sh[2] + sh[3]) * (1.f / 512.f) + 1e-5f);
    float4 sv = *(const float4*)(s + tid * 4);
    float4 bv = *(const float4*)(b + tid * 4);
    float o0 = (v[0] - mu) * inv * sv.x + bv.x;
    float o1 = (v[1] - mu) * inv * sv.y + bv.y;
    float o2 = (v[2] - mu) * inv * sv.z + bv.z;
    float o3 = (v[3] - mu) * inv * sv.w + bv.w;
    *(float4*)(hf + row * 512 + tid * 4) = make_float4(o0, o1, o2, o3);
    ushort4 ub;
    ub.x = f2bf_bits(o0); ub.y = f2bf_bits(o1); ub.z = f2bf_bits(o2); ub.w = f2bf_bits(o3);
    *(ushort4*)(hb + row * 512 + tid * 4) = ub;
}

// ---------------- LN2 + weighted accumulate into d_out; zeroes t for next atomic use ----------------
__global__ __launch_bounds__(128)
void ln2acc_kernel(const float* __restrict__ hf, float* __restrict__ t,
                   const float* __restrict__ s, const float* __restrict__ b,
                   const float* __restrict__ rw, int e, float* __restrict__ out) {
    long row = blockIdx.x;
    float wgt = rw[row * 8 + e];
    int tid = threadIdx.x, w = tid >> 6, lane = tid & 63;
    if (wgt == 0.f) {   // uniform per block: still must zero t for next expert's atomics
        *(float4*)(t + row * 512 + tid * 4) = make_float4(0.f, 0.f, 0.f, 0.f);
        return;
    }
    float4 xv = *(const float4*)(hf + row * 512 + tid * 4);
    float4 tv = *(const float4*)(t + row * 512 + tid * 4);
    *(float4*)(t + row * 512 + tid * 4) = make_float4(0.f, 0.f, 0.f, 0.f);
    float v[4] = {xv.x + tv.x, xv.y + tv.y, xv.z + tv.z, xv.w + tv.w};
    float sum = v[0] + v[1] + v[2] + v[3];
    #pragma unroll
    for (int o = 32; o; o >>= 1) sum += __shfl_down(sum, o, 64);
    __shared__ float sh[4];
    if (lane == 0) sh[w] = sum;
    __syncthreads();
    float mu = (sh[0] + sh[1]) * (1.f / 512.f);
    float sq = 0.f;
    #pragma unroll
    for (int j = 0; j < 4; j++) { float d = v[j] - mu; sq += d * d; }
    #pragma unroll
    for (int o = 32; o; o >>= 1) sq += __shfl_down(sq, o, 64);
    if (lane == 0) sh[2 + w] = sq;
    __syncthreads();
    float inv = 1.f / sqrtf((sh[2] + sh[3]) * (1.f / 512.f) + 1e-5f);
    float4 sv = *(const float4*)(s + tid * 4);
    float4 bv = *(const float4*)(b + tid * 4);
    float4 cur = *(float4*)(out + row * 512 + tid * 4);
    cur.x += wgt * ((v[0] - mu) * inv * sv.x + bv.x);
    cur.y += wgt * ((v[1] - mu) * inv * sv.y + bv.y);
    cur.z += wgt * ((v[2] - mu) * inv * sv.z + bv.z);
    cur.w += wgt * ((v[3] - mu) * inv * sv.w + bv.w);
    *(float4*)(out + row * 512 + tid * 4) = cur;
}

// ---------------- workspace layout (bytes) ----------------
static const size_t OFF_XB  = 0;                                  // bf16 [4096][512]
static const size_t OFF_WB  = OFF_XB  + (size_t)4096*512*2;       // bf16, all transposed weights
static const size_t OFF_RW  = OFF_WB  + (size_t)25165824*2;       // f32 [4096][8]
static const size_t OFF_PB  = OFF_RW  + (size_t)4096*8*4;         // f32 [3][8][512]
static const size_t OFF_QKV = OFF_PB  + (size_t)3*8*512*4;        // bf16 [3][4096][512]
static const size_t OFF_VT  = OFF_QKV + (size_t)3*4096*512*2;     // bf16 [16][128][1024]
static const size_t OFF_S   = OFF_VT  + (size_t)16*128*1024*2;    // bf16 [16][1024][1024]
static const size_t OFF_O   = OFF_S   + (size_t)16*1024*1024*2;   // bf16 [4096][512]
static const size_t OFF_T   = OFF_O   + (size_t)4096*512*2;       // f32  [4096][512] split-K atomic target
static const size_t OFF_HF  = OFF_T   + (size_t)4096*512*4;       // f32  [4096][512]
static const size_t OFF_HB  = OFF_HF  + (size_t)4096*512*4;       // bf16 [4096][512]
static const size_t OFF_MID = OFF_HB  + (size_t)4096*512*2;       // bf16 [4096][2048]
static const size_t OFF_OF  = OFF_MID + (size_t)4096*2048*2;      // f32  [4096][512] PV split-K target

extern "C" void kernel_launch(void* const* d_in, const int* in_sizes, int n_in,
                              void* d_out, int out_size, void* d_ws, size_t ws_size,
                              hipStream_t stream) {
    const float* x      = (const float*)d_in[0];
    const float* gate_w = (const float*)d_in[1];
    const float* gate_b = (const float*)d_in[2];
    const float* ln1_s  = (const float*)d_in[3];
    const float* ln1_b  = (const float*)d_in[4];
    const float* ln2_s  = (const float*)d_in[5];
    const float* ln2_b  = (const float*)d_in[6];
    const float* wq = (const float*)d_in[7];
    const float* wk = (const float*)d_in[8];
    const float* wv = (const float*)d_in[9];
    const float* wo = (const float*)d_in[10];
    const float* bo = (const float*)d_in[14];
    const float* w1 = (const float*)d_in[15];
    const float* b1 = (const float*)d_in[16];
    const float* w2 = (const float*)d_in[17];
    const float* b2 = (const float*)d_in[18];
    float* out = (float*)d_out;

    char* ws = (char*)d_ws;
    u16*   XB  = (u16*)(ws + OFF_XB);
    u16*   WB  = (u16*)(ws + OFF_WB);
    float* RW  = (float*)(ws + OFF_RW);
    float* PB  = (float*)(ws + OFF_PB);
    u16*   QKV = (u16*)(ws + OFF_QKV);
    u16*   VT  = (u16*)(ws + OFF_VT);
    u16*   S   = (u16*)(ws + OFF_S);
    u16*   O   = (u16*)(ws + OFF_O);
    float* T   = (float*)(ws + OFF_T);
    float* HF  = (float*)(ws + OFF_HF);
    u16*   HB  = (u16*)(ws + OFF_HB);
    u16*   MID = (u16*)(ws + OFF_MID);
    float* OF  = (float*)(ws + OFF_OF);

    hipMemsetAsync(d_out, 0, (size_t)4096 * 512 * 4, stream);
    hipMemsetAsync(T,  0, (size_t)4096 * 512 * 4, stream);   // split-K atomic targets start at zero;
    hipMemsetAsync(OF, 0, (size_t)4096 * 512 * 4, stream);   // consumers self-clean for experts 1..7

    cast_bf16_kernel<<<dim3(2048), 256, 0, stream>>>(x, XB, 4096 * 512 / 4);
    transpose_cast_kernel<<<dim3(16,16,8), dim3(32,8), 0, stream>>>(wq, WB + 0,        512,  512,  262144,  262144);
    transpose_cast_kernel<<<dim3(16,16,8), dim3(32,8), 0, stream>>>(wk, WB + 2097152,  512,  512,  262144,  262144);
    transpose_cast_kernel<<<dim3(16,16,8), dim3(32,8), 0, stream>>>(wv, WB + 4194304,  512,  512,  262144,  262144);
    transpose_cast_kernel<<<dim3(16,16,8), dim3(32,8), 0, stream>>>(wo, WB + 6291456,  512,  512,  262144,  262144);
    transpose_cast_kernel<<<dim3(64,16,8), dim3(32,8), 0, stream>>>(w1, WB + 8388608,  512,  2048, 1048576, 1048576);
    transpose_cast_kernel<<<dim3(16,64,8), dim3(32,8), 0, stream>>>(w2, WB + 16777216, 2048, 512,  1048576, 1048576);
    pack_bias_kernel<<<dim3(16,3), 256, 0, stream>>>((const float*)d_in[11], (const float*)d_in[12],
                                                     (const float*)d_in[13], PB);
    router_kernel<<<4096, 512, 0, stream>>>(x, gate_w, gate_b, RW, out + 2097152);

    const float isq = 0.08838834764831845f;  // 1/sqrt(128)

    for (int e = 0; e < 8; e++) {
        // QKV projection: z = 0,1,2 -> Q,K,V
        gemm_kernel<true,false,false,false,u16><<<dim3(4,32,3), 256, 0, stream>>>(
            XB, 512, 0, 0,
            WB + (size_t)e*262144, 512, 2097152, 0,
            QKV, 512, 2097152, 0,
            PB + e*512, 4096, 0,
            1, 1, 1.f, 512);
        // scores = Q K^T / sqrt(dh), z=(b,h)
        gemm_kernel<false,false,true,false,u16><<<dim3(8,8,16), 256, 0, stream>>>(
            QKV, 512, 524288, 128,
            QKV + 2097152, 512, 524288, 128,
            S, 1024, 4194304, 1048576,
            nullptr, 0, 0,
            4, 1, isq, 128);
        softmax_kernel<<<16384, 256, 0, stream>>>(S);
        transpose_v_kernel<<<dim3(32,4,16), dim3(32,8), 0, stream>>>(QKV + 2*2097152, VT);
        // O = P V  (split-K 4, atomic fp32 into OF)
        gemm_kernel<false,false,false,true,float><<<dim3(1,8,64), 256, 0, stream>>>(
            S, 1024, 4194304, 1048576,
            VT, 1024, 524288, 131072,
            OF, 512, 524288, 128,
            nullptr, 0, 0,
            4, 4, 1.f, 1024);
        // OF -> O (bf16), zero OF for next expert
        cast_zero_kernel<<<dim3(2048), 256, 0, stream>>>(OF, O, 4096 * 512 / 4);
        // Wo projection -> T (fp32, split-K 4 atomic, bias at ks==0)
        gemm_kernel<true,false,false,true,float><<<dim3(4,32,4), 256, 0, stream>>>(
            O, 512, 0, 0,
            WB + 6291456 + (size_t)e*262144, 512, 0, 0,
            T, 512, 0, 0,
            bo + e*512, 0, 0,
            1, 4, 1.f, 512);
        ln1_kernel<<<4096, 128, 0, stream>>>(x, T, ln1_s + e*512, ln1_b + e*512, HF, HB);
        // FFN1 + relu -> MID (bf16)
        gemm_kernel<true,true,false,false,u16><<<dim3(16,32,1), 256, 0, stream>>>(
            HB, 512, 0, 0,
            WB + 8388608 + (size_t)e*1048576, 512, 0, 0,
            MID, 2048, 0, 0,
            b1 + e*2048, 0, 0,
            1, 1, 1.f, 512);
        // FFN2 -> T (fp32, split-K 8 atomic, bias at ks==0)
        gemm_kernel<true,false,false,true,float><<<dim3(4,32,8), 256, 0, stream>>>(
            MID, 2048, 0, 0,
            WB + 16777216 + (size_t)e*1048576, 2048, 0, 0,
            T, 512, 0, 0,
            b2 + e*512, 0, 0,
            1, 8, 1.f, 2048);
        ln2acc_kernel<<<4096, 128, 0, stream>>>(HF, T, ln2_s + e*512, ln2_b + e*512, RW, e, out);
    }
}

// Round 4
// 1097.747 us; speedup vs baseline: 1.8067x; 1.8067x over previous
//
#include <hip/hip_runtime.h>
#include <hip/hip_bf16.h>
#include <stdint.h>

using u16 = unsigned short;
typedef float floatx4 __attribute__((ext_vector_type(4)));
typedef __bf16 bfv8 __attribute__((ext_vector_type(8)));

#define AS1 __attribute__((address_space(1)))
#define AS3 __attribute__((address_space(3)))

__device__ __forceinline__ u16 f2bf_bits(float f) {
    __hip_bfloat16 h = __float2bfloat16(f);
    u16 u;
    __builtin_memcpy(&u, &h, 2);
    return u;
}
__device__ __forceinline__ float bf_bits2f(u16 u) {
    __hip_bfloat16 h;
    __builtin_memcpy(&h, &u, 2);
    return __bfloat162float(h);
}
__device__ __forceinline__ void gload_lds16(const void* g, void* l) {
    __builtin_amdgcn_global_load_lds((AS1 void*)(uintptr_t)g, (AS3 void*)l, 16, 0, 0);
}

// ---------------- cast fp32 -> bf16, 4 elems/thread ----------------
__global__ void cast_bf16_kernel(const float* __restrict__ in, u16* __restrict__ out, int n4) {
    int i = blockIdx.x * blockDim.x + threadIdx.x;
    if (i >= n4) return;
    float4 v = ((const float4*)in)[i];
    ushort4 o;
    o.x = f2bf_bits(v.x); o.y = f2bf_bits(v.y); o.z = f2bf_bits(v.z); o.w = f2bf_bits(v.w);
    ((ushort4*)out)[i] = o;
}

// ---------------- transpose+cast fp32 [z][R][C] -> bf16 [z][C][R] ----------------
__global__ void transpose_cast_kernel(const float* __restrict__ src, u16* __restrict__ dst,
                                      int R, int C, long sSrc, long sDst) {
    __shared__ float tile[32][33];
    const float* s = src + (long)blockIdx.z * sSrc;
    u16* d = dst + (long)blockIdx.z * sDst;
    int c0 = blockIdx.x * 32, r0 = blockIdx.y * 32;
    int tx = threadIdx.x, ty = threadIdx.y;
    #pragma unroll
    for (int i = 0; i < 4; i++)
        tile[ty + 8*i][tx] = s[(long)(r0 + ty + 8*i) * C + c0 + tx];
    __syncthreads();
    #pragma unroll
    for (int i = 0; i < 4; i++)
        d[(long)(c0 + ty + 8*i) * R + r0 + tx] = f2bf_bits(tile[tx][ty + 8*i]);
}

// ---------------- transpose V_g [2][4096][512]bf16 -> VT_g [32][128][1024]bf16 ----------------
__global__ void transpose_vg_kernel(const u16* __restrict__ V, u16* __restrict__ VT) {
    __shared__ u16 tile[32][33];
    int z = blockIdx.z;                 // e_local*16 + b*4 + h, z in [0,32)
    int e = z >> 4, b = (z >> 2) & 3, h = z & 3;
    int s0 = blockIdx.x * 32, d0 = blockIdx.y * 32;
    int tx = threadIdx.x, ty = threadIdx.y;
    const u16* Vb = V + (size_t)e * 2097152;
    #pragma unroll
    for (int i = 0; i < 4; i++)
        tile[ty + 8*i][tx] = Vb[(long)(b*1024 + s0 + ty + 8*i) * 512 + h*128 + d0 + tx];
    __syncthreads();
    #pragma unroll
    for (int i = 0; i < 4; i++)
        VT[(size_t)z*131072 + (long)(d0 + ty + 8*i) * 1024 + s0 + tx] = tile[tx][ty + 8*i];
}

// ---------------- pack bq/bk/bv -> PB[3][8][512] ----------------
__global__ void pack_bias_kernel(const float* __restrict__ bq, const float* __restrict__ bk,
                                 const float* __restrict__ bv, float* __restrict__ pb) {
    int i = blockIdx.x * 256 + threadIdx.x;  // 0..4095
    const float* s = blockIdx.y == 0 ? bq : (blockIdx.y == 1 ? bk : bv);
    pb[blockIdx.y * 4096 + i] = s[i];
}

// ---------------- router: logits + Scale-and-Fire routing weights ----------------
__global__ __launch_bounds__(512)
void router_kernel(const float* __restrict__ x, const float* __restrict__ gw,
                   const float* __restrict__ gb, float* __restrict__ rw,
                   float* __restrict__ logits_out) {
    int row = blockIdx.x;
    int w = threadIdx.x >> 6;     // expert 0..7
    int lane = threadIdx.x & 63;
    const float* xr = x + (long)row * 512;
    float sum = 0.f;
    #pragma unroll
    for (int i = 0; i < 8; i++) {
        int d = lane + 64 * i;
        sum += xr[d] * gw[d * 8 + w];
    }
    #pragma unroll
    for (int o = 32; o; o >>= 1) sum += __shfl_down(sum, o, 64);
    __shared__ float lg[8];
    if (lane == 0) lg[w] = sum + gb[w];
    __syncthreads();
    if (threadIdx.x == 0) {
        float l[8];
        #pragma unroll
        for (int e = 0; e < 8; e++) l[e] = lg[e];
        int i1 = 0;
        for (int e = 1; e < 8; e++) if (l[e] > l[i1]) i1 = e;
        int i2 = -1;
        for (int e = 0; e < 8; e++) { if (e == i1) continue; if (i2 < 0 || l[e] > l[i2]) i2 = e; }
        for (int e = 0; e < 8; e++) {
            float v = (e == i1 || e == i2) ? (l[e] > 0.f ? l[e] : 0.f) : 0.f;
            float r = 0.f, mem = v;
            #pragma unroll
            for (int lvl = 0; lvl < 4; lvl++) {
                float thr = 4.0f / (float)(1 << lvl);
                if (mem >= thr) { r += thr; mem -= thr; }
            }
            rw[(long)row * 8 + e] = r;
            logits_out[(long)row * 8 + e] = l[e];
        }
    }
}

// ---------------- GEMM: C[M,N] = A[M,K] @ Bt[N,K]^T (+bias)(relu)(alpha) ----------------
// Tile MT x NT, 4 waves arranged WY x WX (WY*WX==4); per-wave (MT/WY)x(NT/WX).
// 128x128/2x2 = m97 structure; 64x128/1x4 for tall-skinny (PV, FFN2).
template<int MT, int NT, int WY, int WX, bool BIAS, bool RELU, bool SCALE, typename OUT>
__global__ __launch_bounds__(256)
void gemm_kernel(const u16* __restrict__ A, int lda, long sAo, long sAi,
                 const u16* __restrict__ B, int ldb, long sBo, long sBi,
                 OUT* __restrict__ C, int ldc, long sCo, long sCi,
                 const float* __restrict__ bias, long sBiasO, long sBiasI,
                 int zdiv, float alpha, int K) {
    constexpr int MI = MT / WY / 16;
    constexpr int NI = NT / WX / 16;
    __shared__ __align__(16) u16 As[MT * 32];
    __shared__ __align__(16) u16 Bs[NT * 32];
    const int z = blockIdx.z;
    const int zo = z / zdiv, zi = z % zdiv;
    const u16* Ab = A + zo * sAo + zi * sAi + (long)blockIdx.y * MT * lda;
    const u16* Bb = B + zo * sBo + zi * sBi + (long)blockIdx.x * NT * ldb;

    const int tid = threadIdx.x;
    const int w = tid >> 6, lane = tid & 63;
    const int wy = w / WX, wx = w % WX;
    const int lr = lane >> 2, lp = lane & 3;
    const int quad = lane >> 4, mrow = lane & 15;

    floatx4 acc[MI][NI];
    #pragma unroll
    for (int i = 0; i < MI; i++)
        #pragma unroll
        for (int j = 0; j < NI; j++)
            acc[i][j] = floatx4{0.f, 0.f, 0.f, 0.f};

    for (int k0 = 0; k0 < K; k0 += 32) {
        #pragma unroll
        for (int j = 0; j < MT / 64; j++) {
            const int s = w * (MT / 64) + j;
            const int r = s * 16 + lr;
            const int c = lp ^ ((r >> 1) & 3);   // XOR swizzle (16B chunks)
            gload_lds16(Ab + (long)r * lda + k0 + c * 8, As + s * 512);
        }
        #pragma unroll
        for (int j = 0; j < NT / 64; j++) {
            const int s = w * (NT / 64) + j;
            const int r = s * 16 + lr;
            const int c = lp ^ ((r >> 1) & 3);
            gload_lds16(Bb + (long)r * ldb + k0 + c * 8, Bs + s * 512);
        }
        __syncthreads();
        bfv8 af[MI], bfr[NI];
        #pragma unroll
        for (int mi = 0; mi < MI; mi++) {
            const int r = wy * (MT / WY) + mi * 16 + mrow;
            const int p = quad ^ ((r >> 1) & 3);
            af[mi] = *(const bfv8*)&As[r * 32 + p * 8];
        }
        #pragma unroll
        for (int ni = 0; ni < NI; ni++) {
            const int r = wx * (NT / WX) + ni * 16 + mrow;
            const int p = quad ^ ((r >> 1) & 3);
            bfr[ni] = *(const bfv8*)&Bs[r * 32 + p * 8];
        }
        #pragma unroll
        for (int mi = 0; mi < MI; mi++)
            #pragma unroll
            for (int ni = 0; ni < NI; ni++)
                acc[mi][ni] = __builtin_amdgcn_mfma_f32_16x16x32_bf16(af[mi], bfr[ni], acc[mi][ni], 0, 0, 0);
        __syncthreads();
    }

    OUT* Cb = C + zo * sCo + zi * sCi + (long)blockIdx.y * MT * ldc + (long)blockIdx.x * NT;
    const float* biasb = BIAS ? (bias + zo * sBiasO + zi * sBiasI + (long)blockIdx.x * NT) : nullptr;
    #pragma unroll
    for (int ni = 0; ni < NI; ni++) {
        const int col = wx * (NT / WX) + ni * 16 + mrow;
        float bv = 0.f;
        if (BIAS) bv = biasb[col];
        #pragma unroll
        for (int mi = 0; mi < MI; mi++) {
            #pragma unroll
            for (int r = 0; r < 4; r++) {
                const int row = wy * (MT / WY) + mi * 16 + quad * 4 + r;
                float v = acc[mi][ni][r];
                if (SCALE) v *= alpha;
                if (BIAS) v += bv;
                if (RELU) v = fmaxf(v, 0.f);
                if constexpr (sizeof(OUT) == 2)
                    ((u16*)Cb)[(long)row * ldc + col] = f2bf_bits(v);
                else
                    ((float*)Cb)[(long)row * ldc + col] = v;
            }
        }
    }
}

// ---------------- softmax over rows of 1024, in-place on bf16 ----------------
__global__ __launch_bounds__(256)
void softmax_kernel(u16* __restrict__ S) {
    long row = blockIdx.x;
    u16* p = S + row * 1024;
    int t = threadIdx.x, w = t >> 6, lane = t & 63;
    float v[4];
    float mx = -1e30f;
    #pragma unroll
    for (int i = 0; i < 4; i++) {
        v[i] = bf_bits2f(p[t + 256 * i]);
        mx = fmaxf(mx, v[i]);
    }
    #pragma unroll
    for (int o = 32; o; o >>= 1) mx = fmaxf(mx, __shfl_down(mx, o, 64));
    __shared__ float red[8];
    if (lane == 0) red[w] = mx;
    __syncthreads();
    mx = fmaxf(fmaxf(red[0], red[1]), fmaxf(red[2], red[3]));
    float sum = 0.f;
    #pragma unroll
    for (int i = 0; i < 4; i++) { v[i] = __expf(v[i] - mx); sum += v[i]; }
    #pragma unroll
    for (int o = 32; o; o >>= 1) sum += __shfl_down(sum, o, 64);
    if (lane == 0) red[4 + w] = sum;
    __syncthreads();
    float inv = 1.f / (red[4] + red[5] + red[6] + red[7]);
    #pragma unroll
    for (int i = 0; i < 4; i++) p[t + 256 * i] = f2bf_bits(v[i] * inv);
}

// ---------------- LN1 batched over experts: hb = LN(x + t), t bf16, bf16 out ----------------
__global__ __launch_bounds__(128)
void ln1_b8_kernel(const float* __restrict__ x, const u16* __restrict__ t,
                   const float* __restrict__ s_all, const float* __restrict__ b_all,
                   u16* __restrict__ hb) {
    long row = blockIdx.x;            // e*4096 + r
    int e = (int)(row >> 12);
    long r = row & 4095;
    int tid = threadIdx.x, w = tid >> 6, lane = tid & 63;
    float4 xv = *(const float4*)(x + r * 512 + tid * 4);
    ushort4 tu = *(const ushort4*)(t + row * 512 + tid * 4);
    float v[4] = {xv.x + bf_bits2f(tu.x), xv.y + bf_bits2f(tu.y),
                  xv.z + bf_bits2f(tu.z), xv.w + bf_bits2f(tu.w)};
    float sum = v[0] + v[1] + v[2] + v[3];
    #pragma unroll
    for (int o = 32; o; o >>= 1) sum += __shfl_down(sum, o, 64);
    __shared__ float sh[4];
    if (lane == 0) sh[w] = sum;
    __syncthreads();
    float mu = (sh[0] + sh[1]) * (1.f / 512.f);
    float sq = 0.f;
    #pragma unroll
    for (int j = 0; j < 4; j++) { float d = v[j] - mu; sq += d * d; }
    #pragma unroll
    for (int o = 32; o; o >>= 1) sq += __shfl_down(sq, o, 64);
    if (lane == 0) sh[2 + w] = sq;
    __syncthreads();
    float inv = 1.f / sqrtf((sh[2] + sh[3]) * (1.f / 512.f) + 1e-5f);
    float4 sv = *(const float4*)(s_all + e * 512 + tid * 4);
    float4 bv = *(const float4*)(b_all + e * 512 + tid * 4);
    ushort4 ub;
    ub.x = f2bf_bits((v[0] - mu) * inv * sv.x + bv.x);
    ub.y = f2bf_bits((v[1] - mu) * inv * sv.y + bv.y);
    ub.z = f2bf_bits((v[2] - mu) * inv * sv.z + bv.z);
    ub.w = f2bf_bits((v[3] - mu) * inv * sv.w + bv.w);
    *(ushort4*)(hb + row * 512 + tid * 4) = ub;
}

// ---------------- LN2 + weighted accumulate over all 8 experts, one block per row ----------------
__global__ __launch_bounds__(128)
void ln2acc_all_kernel(const u16* __restrict__ hb, const u16* __restrict__ t2,
                       const float* __restrict__ s_all, const float* __restrict__ b_all,
                       const float* __restrict__ rw, float* __restrict__ out) {
    long r = blockIdx.x;
    int tid = threadIdx.x, w = tid >> 6, lane = tid & 63;
    __shared__ float sh[4];
    float4 acc = make_float4(0.f, 0.f, 0.f, 0.f);
    for (int e = 0; e < 8; e++) {
        float wgt = rw[r * 8 + e];
        if (wgt != 0.f) {   // block-uniform branch (wgt depends only on blockIdx)
            long row = (long)e * 4096 + r;
            ushort4 hu = *(const ushort4*)(hb + row * 512 + tid * 4);
            ushort4 fu = *(const ushort4*)(t2 + row * 512 + tid * 4);
            float v[4] = {bf_bits2f(hu.x) + bf_bits2f(fu.x), bf_bits2f(hu.y) + bf_bits2f(fu.y),
                          bf_bits2f(hu.z) + bf_bits2f(fu.z), bf_bits2f(hu.w) + bf_bits2f(fu.w)};
            float sum = v[0] + v[1] + v[2] + v[3];
            #pragma unroll
            for (int o = 32; o; o >>= 1) sum += __shfl_down(sum, o, 64);
            if (lane == 0) sh[w] = sum;
            __syncthreads();
            float mu = (sh[0] + sh[1]) * (1.f / 512.f);
            float sq = 0.f;
            #pragma unroll
            for (int j = 0; j < 4; j++) { float d = v[j] - mu; sq += d * d; }
            #pragma unroll
            for (int o = 32; o; o >>= 1) sq += __shfl_down(sq, o, 64);
            if (lane == 0) sh[2 + w] = sq;
            __syncthreads();
            float inv = 1.f / sqrtf((sh[2] + sh[3]) * (1.f / 512.f) + 1e-5f);
            float4 sv = *(const float4*)(s_all + e * 512 + tid * 4);
            float4 bv = *(const float4*)(b_all + e * 512 + tid * 4);
            acc.x += wgt * ((v[0] - mu) * inv * sv.x + bv.x);
            acc.y += wgt * ((v[1] - mu) * inv * sv.y + bv.y);
            acc.z += wgt * ((v[2] - mu) * inv * sv.z + bv.z);
            acc.w += wgt * ((v[3] - mu) * inv * sv.w + bv.w);
            __syncthreads();   // protect sh[] before next expert
        }
    }
    *(float4*)(out + r * 512 + tid * 4) = acc;
}

// ---------------- workspace layout (bytes), peak 155,385,856 < 163,758,080 (proven in R1) ----
// [0,48M)      WB     all weights bf16 transposed                        whole call
// 48M..        RW(128K) PB(48K+pad)                                      whole call
// XB   4MB     bf16 x                                                    QKV phase
// O8   32MB    bf16 attention out, all experts                           attn -> Wo
// attn scratch (per 2-expert group): QKVg 24MB | VTg 8MB | S 32MB        attn only
//   aliased after attn:  T8 32MB (Wo out) | HB8 32MB (ln1 out)
// FFN: MID_2 32MB @ XB+O8 region; T2 32MB @ T8 region (T8 dead post-LN1)
static const size_t WB_B   = 0;
static const size_t RW_B   = 50331648;
static const size_t PB_B   = 50462720;
static const size_t XB_B   = 50528256;
static const size_t O8_B   = 54722560;
static const size_t QKVG_B = 88276992;
static const size_t VTG_B  = 113442816;
static const size_t S_B    = 121831424;   // end 155385856
static const size_t T8_B   = 88276992;
static const size_t HB_B   = 121831424;
static const size_t MID_B  = 54722560;
static const size_t T2_B   = 88276992;

extern "C" void kernel_launch(void* const* d_in, const int* in_sizes, int n_in,
                              void* d_out, int out_size, void* d_ws, size_t ws_size,
                              hipStream_t stream) {
    const float* x      = (const float*)d_in[0];
    const float* gate_w = (const float*)d_in[1];
    const float* gate_b = (const float*)d_in[2];
    const float* ln1_s  = (const float*)d_in[3];
    const float* ln1_b  = (const float*)d_in[4];
    const float* ln2_s  = (const float*)d_in[5];
    const float* ln2_b  = (const float*)d_in[6];
    const float* wq = (const float*)d_in[7];
    const float* wk = (const float*)d_in[8];
    const float* wv = (const float*)d_in[9];
    const float* wo = (const float*)d_in[10];
    const float* bo = (const float*)d_in[14];
    const float* w1 = (const float*)d_in[15];
    const float* b1 = (const float*)d_in[16];
    const float* w2 = (const float*)d_in[17];
    const float* b2 = (const float*)d_in[18];
    float* out = (float*)d_out;

    char* ws = (char*)d_ws;
    u16*   WB   = (u16*)(ws + WB_B);
    float* RW   = (float*)(ws + RW_B);
    float* PB   = (float*)(ws + PB_B);
    u16*   XB   = (u16*)(ws + XB_B);
    u16*   O8   = (u16*)(ws + O8_B);
    u16*   QKVg = (u16*)(ws + QKVG_B);  // [t][de][4096][512]
    u16*   VTg  = (u16*)(ws + VTG_B);   // [de*16+b*4+h][128][1024]
    u16*   S    = (u16*)(ws + S_B);     // [b*4+h][1024][1024] one expert
    u16*   T8   = (u16*)(ws + T8_B);    // [8][4096][512]
    u16*   HB8  = (u16*)(ws + HB_B);    // [8][4096][512]
    u16*   MID  = (u16*)(ws + MID_B);   // [2][4096][2048]
    u16*   T2   = (u16*)(ws + T2_B);    // [8][4096][512]

    // ---- setup ----
    cast_bf16_kernel<<<dim3(2048), 256, 0, stream>>>(x, XB, 4096 * 512 / 4);
    transpose_cast_kernel<<<dim3(16,16,8), dim3(32,8), 0, stream>>>(wq, WB + 0,        512,  512,  262144,  262144);
    transpose_cast_kernel<<<dim3(16,16,8), dim3(32,8), 0, stream>>>(wk, WB + 2097152,  512,  512,  262144,  262144);
    transpose_cast_kernel<<<dim3(16,16,8), dim3(32,8), 0, stream>>>(wv, WB + 4194304,  512,  512,  262144,  262144);
    transpose_cast_kernel<<<dim3(16,16,8), dim3(32,8), 0, stream>>>(wo, WB + 6291456,  512,  512,  262144,  262144);
    transpose_cast_kernel<<<dim3(64,16,8), dim3(32,8), 0, stream>>>(w1, WB + 8388608,  512,  2048, 1048576, 1048576);
    transpose_cast_kernel<<<dim3(16,64,8), dim3(32,8), 0, stream>>>(w2, WB + 16777216, 2048, 512,  1048576, 1048576);
    pack_bias_kernel<<<dim3(16,3), 256, 0, stream>>>((const float*)d_in[11], (const float*)d_in[12],
                                                     (const float*)d_in[13], PB);
    router_kernel<<<4096, 512, 0, stream>>>(x, gate_w, gate_b, RW, out + 2097152);

    const float isq = 0.08838834764831845f;  // 1/sqrt(128)

    // ---- attention in 4 groups of 2 experts ----
    for (int g = 0; g < 4; g++) {
        int e0 = 2 * g;
        // QKV for the pair: z = t*2 + de
        gemm_kernel<128,128,2,2,true,false,false,u16><<<dim3(4,32,6), 256, 0, stream>>>(
            XB, 512, 0, 0,
            WB + (size_t)e0*262144, 512, 2097152, 262144,
            QKVg, 512, 4194304, 2097152,
            PB + e0*512, 4096, 512,
            2, 1.f, 512);
        transpose_vg_kernel<<<dim3(32,4,32), dim3(32,8), 0, stream>>>(QKVg + 8388608, VTg);
        for (int de = 0; de < 2; de++) {
            // scores = Q K^T * isq ; z = b*4+h
            gemm_kernel<128,128,2,2,false,false,true,u16><<<dim3(8,8,16), 256, 0, stream>>>(
                QKVg + (size_t)de*2097152,           512, 524288, 128,
                QKVg + 4194304 + (size_t)de*2097152, 512, 524288, 128,
                S, 1024, 4194304, 1048576,
                nullptr, 0, 0,
                4, isq, 128);
            softmax_kernel<<<16384, 256, 0, stream>>>(S);
            // O = P V ; 64x128 tiles for a bigger grid
            gemm_kernel<64,128,1,4,false,false,false,u16><<<dim3(1,16,16), 256, 0, stream>>>(
                S, 1024, 4194304, 1048576,
                VTg + (size_t)de*2097152, 1024, 524288, 131072,
                O8 + (size_t)(e0 + de)*2097152, 512, 524288, 128,
                nullptr, 0, 0,
                4, 1.f, 1024);
        }
    }

    // ---- Wo all experts -> T8 (bf16) ----
    gemm_kernel<128,128,2,2,true,false,false,u16><<<dim3(4,32,8), 256, 0, stream>>>(
        O8, 512, 2097152, 0,
        WB + 6291456, 512, 262144, 0,
        T8, 512, 2097152, 0,
        bo, 512, 0,
        1, 1.f, 512);

    // ---- LN1 batched -> HB8 (bf16) ----
    ln1_b8_kernel<<<32768, 128, 0, stream>>>(x, T8, ln1_s, ln1_b, HB8);

    // ---- FFN in 4 groups of 2 experts ----
    for (int g = 0; g < 4; g++) {
        int e0 = 2 * g;
        gemm_kernel<128,128,2,2,true,true,false,u16><<<dim3(16,32,2), 256, 0, stream>>>(
            HB8 + (size_t)e0*2097152, 512, 2097152, 0,
            WB + 8388608 + (size_t)e0*1048576, 512, 1048576, 0,
            MID, 2048, 8388608, 0,
            b1 + e0*2048, 2048, 0,
            1, 1.f, 512);
        gemm_kernel<64,128,1,4,true,false,false,u16><<<dim3(4,64,2), 256, 0, stream>>>(
            MID, 2048, 8388608, 0,
            WB + 16777216 + (size_t)e0*1048576, 2048, 1048576, 0,
            T2 + (size_t)e0*2097152, 512, 2097152, 0,
            b2 + e0*512, 512, 0,
            1, 1.f, 2048);
    }

    // ---- LN2 + routing-weighted accumulate -> out ----
    ln2acc_all_kernel<<<4096, 128, 0, stream>>>(HB8, T2, ln2_s, ln2_b, RW, out);
}

// Round 5
// 1019.745 us; speedup vs baseline: 1.9449x; 1.0765x over previous
//
#include <hip/hip_runtime.h>
#include <hip/hip_bf16.h>
#include <stdint.h>

using u16 = unsigned short;
typedef float floatx4 __attribute__((ext_vector_type(4)));
typedef __bf16 bfv8 __attribute__((ext_vector_type(8)));

#define AS1 __attribute__((address_space(1)))
#define AS3 __attribute__((address_space(3)))

__device__ __forceinline__ u16 f2bf_bits(float f) {
    __hip_bfloat16 h = __float2bfloat16(f);
    u16 u;
    __builtin_memcpy(&u, &h, 2);
    return u;
}
__device__ __forceinline__ float bf_bits2f(u16 u) {
    __hip_bfloat16 h;
    __builtin_memcpy(&h, &u, 2);
    return __bfloat162float(h);
}
__device__ __forceinline__ void gload_lds16(const void* g, void* l) {
    __builtin_amdgcn_global_load_lds((AS1 void*)(uintptr_t)g, (AS3 void*)l, 16, 0, 0);
}

// ---------------- cast fp32 -> bf16 ----------------
__global__ void cast_bf16_kernel(const float* __restrict__ in, u16* __restrict__ out, int n4) {
    int i = blockIdx.x * blockDim.x + threadIdx.x;
    if (i >= n4) return;
    float4 v = ((const float4*)in)[i];
    ushort4 o;
    o.x = f2bf_bits(v.x); o.y = f2bf_bits(v.y); o.z = f2bf_bits(v.z); o.w = f2bf_bits(v.w);
    ((ushort4*)out)[i] = o;
}

// ---------------- transpose+cast fp32 [z][R][C] -> bf16 [z][C][R] ----------------
__global__ void transpose_cast_kernel(const float* __restrict__ src, u16* __restrict__ dst,
                                      int R, int C, long sSrc, long sDst) {
    __shared__ float tile[32][33];
    const float* s = src + (long)blockIdx.z * sSrc;
    u16* d = dst + (long)blockIdx.z * sDst;
    int c0 = blockIdx.x * 32, r0 = blockIdx.y * 32;
    int tx = threadIdx.x, ty = threadIdx.y;
    #pragma unroll
    for (int i = 0; i < 4; i++)
        tile[ty + 8*i][tx] = s[(long)(r0 + ty + 8*i) * C + c0 + tx];
    __syncthreads();
    #pragma unroll
    for (int i = 0; i < 4; i++)
        d[(long)(c0 + ty + 8*i) * R + r0 + tx] = f2bf_bits(tile[tx][ty + 8*i]);
}

// ---------------- pack bq/bk/bv -> PB[3][8][512] ----------------
__global__ void pack_bias_kernel(const float* __restrict__ bq, const float* __restrict__ bk,
                                 const float* __restrict__ bv, float* __restrict__ pb) {
    int i = blockIdx.x * 256 + threadIdx.x;
    const float* s = blockIdx.y == 0 ? bq : (blockIdx.y == 1 ? bk : bv);
    pb[blockIdx.y * 4096 + i] = s[i];
}

// ---------------- router ----------------
__global__ __launch_bounds__(512)
void router_kernel(const float* __restrict__ x, const float* __restrict__ gw,
                   const float* __restrict__ gb, float* __restrict__ rw,
                   float* __restrict__ logits_out) {
    int row = blockIdx.x;
    int w = threadIdx.x >> 6;
    int lane = threadIdx.x & 63;
    const float* xr = x + (long)row * 512;
    float sum = 0.f;
    #pragma unroll
    for (int i = 0; i < 8; i++) {
        int d = lane + 64 * i;
        sum += xr[d] * gw[d * 8 + w];
    }
    #pragma unroll
    for (int o = 32; o; o >>= 1) sum += __shfl_down(sum, o, 64);
    __shared__ float lg[8];
    if (lane == 0) lg[w] = sum + gb[w];
    __syncthreads();
    if (threadIdx.x == 0) {
        float l[8];
        #pragma unroll
        for (int e = 0; e < 8; e++) l[e] = lg[e];
        int i1 = 0;
        for (int e = 1; e < 8; e++) if (l[e] > l[i1]) i1 = e;
        int i2 = -1;
        for (int e = 0; e < 8; e++) { if (e == i1) continue; if (i2 < 0 || l[e] > l[i2]) i2 = e; }
        for (int e = 0; e < 8; e++) {
            float v = (e == i1 || e == i2) ? (l[e] > 0.f ? l[e] : 0.f) : 0.f;
            float r = 0.f, mem = v;
            #pragma unroll
            for (int lvl = 0; lvl < 4; lvl++) {
                float thr = 4.0f / (float)(1 << lvl);
                if (mem >= thr) { r += thr; mem -= thr; }
            }
            rw[(long)row * 8 + e] = r;
            logits_out[(long)row * 8 + e] = l[e];
        }
    }
}

// ---------------- build per-(e,b) compacted row lists ----------------
// grid 32 blocks (e = blk>>2, b = blk&3), 256 threads
__global__ __launch_bounds__(256)
void build_lists_kernel(const float* __restrict__ rw, int* __restrict__ rix,
                        int* __restrict__ smap, int* __restrict__ cnt, int* __restrict__ cntpad) {
    int e = blockIdx.x >> 2, b = blockIdx.x & 3;
    int t = threadIdx.x;
    __shared__ int pc[256];
    __shared__ int totsh;
    int r0 = b * 1024 + t * 4;
    int f[4];
    int c = 0;
    #pragma unroll
    for (int i = 0; i < 4; i++) {
        f[i] = (rw[(long)(r0 + i) * 8 + e] != 0.f) ? 1 : 0;
        c += f[i];
    }
    pc[t] = c;
    __syncthreads();
    if (t == 0) {
        int run = 0;
        for (int i = 0; i < 256; i++) { int v = pc[i]; pc[i] = run; run += v; }
        totsh = run;
    }
    __syncthreads();
    int slot = pc[t];
    #pragma unroll
    for (int i = 0; i < 4; i++) {
        int r = r0 + i;
        if (f[i]) {
            rix[e * 4096 + b * 1024 + slot] = r;
            smap[(long)r * 8 + e] = b * 1024 + slot;
            slot++;
        } else {
            smap[(long)r * 8 + e] = -1;
        }
    }
    int tot = totsh;
    for (int s = tot + t; s < 1024; s += 256) rix[e * 4096 + b * 1024 + s] = b * 1024;  // safe pad row
    if (t == 0) {
        cnt[blockIdx.x] = tot;
        cntpad[blockIdx.x] = (tot + 127) & ~127;
    }
}

// ---------------- GEMM: C[M,N] = A[M,K] @ Bt[N,K]^T ----------------
// IDX: A rows gathered via ridx[zo*1024 + tile_row]. mcnt: padded-count early exit per zo.
// TRANSC: write C into VT layout [(b*4+h)][128][1024] (V-projection direct transpose).
template<bool BIAS, bool RELU, bool SCALE, bool IDX, bool TRANSC>
__global__ __launch_bounds__(256)
void gemm_kernel(const u16* __restrict__ A, int lda, long sAo, long sAi,
                 const u16* __restrict__ B, int ldb, long sBo, long sBi,
                 u16* __restrict__ C, int ldc, long sCo, long sCi,
                 const float* __restrict__ bias, long sBiasO, long sBiasI,
                 int zdiv, float alpha, int K,
                 const int* __restrict__ ridx, const int* __restrict__ mcnt) {
    __shared__ __align__(16) u16 As[128 * 32];
    __shared__ __align__(16) u16 Bs[128 * 32];
    const int z = blockIdx.z;
    const int zo = z / zdiv, zi = z % zdiv;
    if (mcnt && (int)blockIdx.y * 128 >= mcnt[zo]) return;

    const u16* Abase = A + zo * sAo + zi * sAi;
    const u16* Bb = B + zo * sBo + zi * sBi + (long)blockIdx.x * 128 * ldb;

    const int tid = threadIdx.x;
    const int w = tid >> 6, lane = tid & 63;
    const int wy = w >> 1, wx = w & 1;
    const int lr = lane >> 2, lp = lane & 3;
    const int quad = lane >> 4, mrow = lane & 15;

    floatx4 acc[4][4];
    #pragma unroll
    for (int i = 0; i < 4; i++)
        #pragma unroll
        for (int j = 0; j < 4; j++)
            acc[i][j] = floatx4{0.f, 0.f, 0.f, 0.f};

    // per-thread A source rows (2 stages of 16B per wave-segment)
    long arow[2];
    #pragma unroll
    for (int j = 0; j < 2; j++) {
        const int r = (w * 2 + j) * 16 + lr;
        if (IDX) arow[j] = ridx[zo * 1024 + blockIdx.y * 128 + r];
        else     arow[j] = (long)blockIdx.y * 128 + r;
    }

    for (int k0 = 0; k0 < K; k0 += 32) {
        #pragma unroll
        for (int j = 0; j < 2; j++) {
            const int s = w * 2 + j;
            const int r = s * 16 + lr;
            const int c = lp ^ ((r >> 1) & 3);
            gload_lds16(Abase + arow[j] * lda + k0 + c * 8, As + s * 512);
            gload_lds16(Bb + (long)r * ldb + k0 + c * 8, Bs + s * 512);
        }
        __syncthreads();
        bfv8 af[4], bfr[4];
        #pragma unroll
        for (int mi = 0; mi < 4; mi++) {
            const int r = wy * 64 + mi * 16 + mrow;
            const int p = quad ^ ((r >> 1) & 3);
            af[mi] = *(const bfv8*)&As[r * 32 + p * 8];
        }
        #pragma unroll
        for (int ni = 0; ni < 4; ni++) {
            const int r = wx * 64 + ni * 16 + mrow;
            const int p = quad ^ ((r >> 1) & 3);
            bfr[ni] = *(const bfv8*)&Bs[r * 32 + p * 8];
        }
        #pragma unroll
        for (int mi = 0; mi < 4; mi++)
            #pragma unroll
            for (int ni = 0; ni < 4; ni++)
                acc[mi][ni] = __builtin_amdgcn_mfma_f32_16x16x32_bf16(af[mi], bfr[ni], acc[mi][ni], 0, 0, 0);
        __syncthreads();
    }

    const float* biasb = BIAS ? (bias + zo * sBiasO + zi * sBiasI + (long)blockIdx.x * 128) : nullptr;
    if constexpr (TRANSC) {
        u16* Cb = C + zo * sCo + zi * sCi;
        #pragma unroll
        for (int ni = 0; ni < 4; ni++) {
            const int colt = wx * 64 + ni * 16 + mrow;
            const int n = blockIdx.x * 128 + colt;
            float bv = BIAS ? biasb[colt] : 0.f;
            #pragma unroll
            for (int mi = 0; mi < 4; mi++) {
                #pragma unroll
                for (int r = 0; r < 4; r++) {
                    const int m = blockIdx.y * 128 + wy * 64 + mi * 16 + quad * 4 + r;
                    float v = acc[mi][ni][r];
                    if (BIAS) v += bv;
                    // VT[(b*4+h)][d][k] : b=m>>10, k=m&1023, h=n>>7, d=n&127
                    long addr = ((long)(((m >> 10) << 2) + (n >> 7)) * 128 + (n & 127)) * 1024 + (m & 1023);
                    Cb[addr] = f2bf_bits(v);
                }
            }
        }
    } else {
        u16* Cb = C + zo * sCo + zi * sCi + (long)blockIdx.y * 128 * ldc + (long)blockIdx.x * 128;
        #pragma unroll
        for (int ni = 0; ni < 4; ni++) {
            const int col = wx * 64 + ni * 16 + mrow;
            float bv = 0.f;
            if (BIAS) bv = biasb[col];
            #pragma unroll
            for (int mi = 0; mi < 4; mi++) {
                #pragma unroll
                for (int r = 0; r < 4; r++) {
                    const int row = wy * 64 + mi * 16 + quad * 4 + r;
                    float v = acc[mi][ni][r];
                    if (SCALE) v *= alpha;
                    if (BIAS) v += bv;
                    if (RELU) v = fmaxf(v, 0.f);
                    Cb[(long)row * ldc + col] = f2bf_bits(v);
                }
            }
        }
    }
}

// ---------------- compacted (e,b,mtile) GEMM for Wo / FFN1 / FFN2 ----------------
// y -> mt=y&7, b=(y>>3)&3, el=y>>5 ; rows live at (el*4+b)*1024 + mt*128 (+bias, optional relu)
template<bool RELU>
__global__ __launch_bounds__(256)
void gemm_eb_kernel(const u16* __restrict__ A, int lda,
                    const u16* __restrict__ B, int ldb, long sBe,
                    u16* __restrict__ C, int ldc,
                    const float* __restrict__ bias, long sBiasE,
                    const int* __restrict__ cntp, int K) {
    __shared__ __align__(16) u16 As[128 * 32];
    __shared__ __align__(16) u16 Bs[128 * 32];
    const int y = blockIdx.y;
    const int mt = y & 7, b = (y >> 3) & 3, el = y >> 5;
    if (mt * 128 >= cntp[el * 4 + b]) return;
    const long rbase = (long)(((el * 4 + b) << 10) + mt * 128);
    const u16* Ab = A + rbase * lda;
    const u16* Bb = B + (long)el * sBe + (long)blockIdx.x * 128 * ldb;

    const int tid = threadIdx.x;
    const int w = tid >> 6, lane = tid & 63;
    const int wy = w >> 1, wx = w & 1;
    const int lr = lane >> 2, lp = lane & 3;
    const int quad = lane >> 4, mrow = lane & 15;

    floatx4 acc[4][4];
    #pragma unroll
    for (int i = 0; i < 4; i++)
        #pragma unroll
        for (int j = 0; j < 4; j++)
            acc[i][j] = floatx4{0.f, 0.f, 0.f, 0.f};

    for (int k0 = 0; k0 < K; k0 += 32) {
        #pragma unroll
        for (int j = 0; j < 2; j++) {
            const int s = w * 2 + j;
            const int r = s * 16 + lr;
            const int c = lp ^ ((r >> 1) & 3);
            gload_lds16(Ab + (long)r * lda + k0 + c * 8, As + s * 512);
            gload_lds16(Bb + (long)r * ldb + k0 + c * 8, Bs + s * 512);
        }
        __syncthreads();
        bfv8 af[4], bfr[4];
        #pragma unroll
        for (int mi = 0; mi < 4; mi++) {
            const int r = wy * 64 + mi * 16 + mrow;
            const int p = quad ^ ((r >> 1) & 3);
            af[mi] = *(const bfv8*)&As[r * 32 + p * 8];
        }
        #pragma unroll
        for (int ni = 0; ni < 4; ni++) {
            const int r = wx * 64 + ni * 16 + mrow;
            const int p = quad ^ ((r >> 1) & 3);
            bfr[ni] = *(const bfv8*)&Bs[r * 32 + p * 8];
        }
        #pragma unroll
        for (int mi = 0; mi < 4; mi++)
            #pragma unroll
            for (int ni = 0; ni < 4; ni++)
                acc[mi][ni] = __builtin_amdgcn_mfma_f32_16x16x32_bf16(af[mi], bfr[ni], acc[mi][ni], 0, 0, 0);
        __syncthreads();
    }

    u16* Cb = C + rbase * ldc + (long)blockIdx.x * 128;
    const float* biasb = bias + el * sBiasE + (long)blockIdx.x * 128;
    #pragma unroll
    for (int ni = 0; ni < 4; ni++) {
        const int col = wx * 64 + ni * 16 + mrow;
        float bv = biasb[col];
        #pragma unroll
        for (int mi = 0; mi < 4; mi++) {
            #pragma unroll
            for (int r = 0; r < 4; r++) {
                const int row = wy * 64 + mi * 16 + quad * 4 + r;
                float v = acc[mi][ni][r] + bv;
                if (RELU) v = fmaxf(v, 0.f);
                Cb[(long)row * ldc + col] = f2bf_bits(v);
            }
        }
    }
}

// ---------------- softmax over rows of 1024, compacted rows only ----------------
__global__ __launch_bounds__(256)
void softmax_kernel(u16* __restrict__ S, const int* __restrict__ cnt) {
    int idx = blockIdx.x;                  // (b*4+h)*1024 + slot
    int slot = idx & 1023;
    int b = idx >> 12;
    if (slot >= cnt[b]) return;
    u16* p = S + (long)idx * 1024;
    int t = threadIdx.x, w = t >> 6, lane = t & 63;
    float v[4];
    float mx = -1e30f;
    #pragma unroll
    for (int i = 0; i < 4; i++) {
        v[i] = bf_bits2f(p[t + 256 * i]);
        mx = fmaxf(mx, v[i]);
    }
    #pragma unroll
    for (int o = 32; o; o >>= 1) mx = fmaxf(mx, __shfl_down(mx, o, 64));
    __shared__ float red[8];
    if (lane == 0) red[w] = mx;
    __syncthreads();
    mx = fmaxf(fmaxf(red[0], red[1]), fmaxf(red[2], red[3]));
    float sum = 0.f;
    #pragma unroll
    for (int i = 0; i < 4; i++) { v[i] = __expf(v[i] - mx); sum += v[i]; }
    #pragma unroll
    for (int o = 32; o; o >>= 1) sum += __shfl_down(sum, o, 64);
    if (lane == 0) red[4 + w] = sum;
    __syncthreads();
    float inv = 1.f / (red[4] + red[5] + red[6] + red[7]);
    #pragma unroll
    for (int i = 0; i < 4; i++) p[t + 256 * i] = f2bf_bits(v[i] * inv);
}

// ---------------- LN1 on compacted rows: hb = LN(x[rowidx] + t) ----------------
// grid 32768 = e(3b) | b(2b) | slot(10b); zero-fills padded-tile rows.
__global__ __launch_bounds__(128)
void ln1c_kernel(const float* __restrict__ x, const u16* __restrict__ t,
                 const int* __restrict__ rix, const int* __restrict__ cnt,
                 const int* __restrict__ cntpad,
                 const float* __restrict__ s_all, const float* __restrict__ b_all,
                 u16* __restrict__ hb) {
    int blk = blockIdx.x;
    int e = blk >> 12, b = (blk >> 10) & 3, sl = blk & 1023;
    int idx = e * 4 + b;
    if (sl >= cntpad[idx]) return;
    long rowc = (long)e * 4096 + b * 1024 + sl;
    int tid = threadIdx.x, w = tid >> 6, lane = tid & 63;
    if (sl >= cnt[idx]) {
        *(ushort4*)(hb + rowc * 512 + tid * 4) = make_ushort4(0, 0, 0, 0);
        return;
    }
    int r = rix[e * 4096 + b * 1024 + sl];
    float4 xv = *(const float4*)(x + (long)r * 512 + tid * 4);
    ushort4 tu = *(const ushort4*)(t + rowc * 512 + tid * 4);
    float v[4] = {xv.x + bf_bits2f(tu.x), xv.y + bf_bits2f(tu.y),
                  xv.z + bf_bits2f(tu.z), xv.w + bf_bits2f(tu.w)};
    float sum = v[0] + v[1] + v[2] + v[3];
    #pragma unroll
    for (int o = 32; o; o >>= 1) sum += __shfl_down(sum, o, 64);
    __shared__ float sh[4];
    if (lane == 0) sh[w] = sum;
    __syncthreads();
    float mu = (sh[0] + sh[1]) * (1.f / 512.f);
    float sq = 0.f;
    #pragma unroll
    for (int j = 0; j < 4; j++) { float d = v[j] - mu; sq += d * d; }
    #pragma unroll
    for (int o = 32; o; o >>= 1) sq += __shfl_down(sq, o, 64);
    if (lane == 0) sh[2 + w] = sq;
    __syncthreads();
    float inv = 1.f / sqrtf((sh[2] + sh[3]) * (1.f / 512.f) + 1e-5f);
    float4 sv = *(const float4*)(s_all + e * 512 + tid * 4);
    float4 bv = *(const float4*)(b_all + e * 512 + tid * 4);
    ushort4 ub;
    ub.x = f2bf_bits((v[0] - mu) * inv * sv.x + bv.x);
    ub.y = f2bf_bits((v[1] - mu) * inv * sv.y + bv.y);
    ub.z = f2bf_bits((v[2] - mu) * inv * sv.z + bv.z);
    ub.w = f2bf_bits((v[3] - mu) * inv * sv.w + bv.w);
    *(ushort4*)(hb + rowc * 512 + tid * 4) = ub;
}

// ---------------- LN2 + weighted accumulate for a pair of experts ----------------
__global__ __launch_bounds__(128)
void ln2acc_pair_kernel(const u16* __restrict__ hb, const u16* __restrict__ t2,
                        const float* __restrict__ s_all, const float* __restrict__ b_all,
                        const float* __restrict__ rw, const int* __restrict__ smap,
                        int e0, int init, float* __restrict__ out) {
    long r = blockIdx.x;
    int tid = threadIdx.x, w = tid >> 6, lane = tid & 63;
    __shared__ float sh[4];
    float4 acc = make_float4(0.f, 0.f, 0.f, 0.f);
    for (int el = 0; el < 2; el++) {
        int e = e0 + el;
        int sl = smap[r * 8 + e];
        if (sl >= 0) {   // block-uniform
            float wgt = rw[r * 8 + e];
            long rh = (long)e * 4096 + sl;
            long rt = (long)el * 4096 + sl;
            ushort4 hu = *(const ushort4*)(hb + rh * 512 + tid * 4);
            ushort4 fu = *(const ushort4*)(t2 + rt * 512 + tid * 4);
            float v[4] = {bf_bits2f(hu.x) + bf_bits2f(fu.x), bf_bits2f(hu.y) + bf_bits2f(fu.y),
                          bf_bits2f(hu.z) + bf_bits2f(fu.z), bf_bits2f(hu.w) + bf_bits2f(fu.w)};
            float sum = v[0] + v[1] + v[2] + v[3];
            #pragma unroll
            for (int o = 32; o; o >>= 1) sum += __shfl_down(sum, o, 64);
            if (lane == 0) sh[w] = sum;
            __syncthreads();
            float mu = (sh[0] + sh[1]) * (1.f / 512.f);
            float sq = 0.f;
            #pragma unroll
            for (int j = 0; j < 4; j++) { float d = v[j] - mu; sq += d * d; }
            #pragma unroll
            for (int o = 32; o; o >>= 1) sq += __shfl_down(sq, o, 64);
            if (lane == 0) sh[2 + w] = sq;
            __syncthreads();
            float inv = 1.f / sqrtf((sh[2] + sh[3]) * (1.f / 512.f) + 1e-5f);
            float4 sv = *(const float4*)(s_all + e * 512 + tid * 4);
            float4 bv = *(const float4*)(b_all + e * 512 + tid * 4);
            acc.x += wgt * ((v[0] - mu) * inv * sv.x + bv.x);
            acc.y += wgt * ((v[1] - mu) * inv * sv.y + bv.y);
            acc.z += wgt * ((v[2] - mu) * inv * sv.z + bv.z);
            acc.w += wgt * ((v[3] - mu) * inv * sv.w + bv.w);
            __syncthreads();
        }
    }
    float* op = out + r * 512 + tid * 4;
    if (init) {
        *(float4*)op = acc;
    } else {
        float4 cur = *(float4*)op;
        cur.x += acc.x; cur.y += acc.y; cur.z += acc.z; cur.w += acc.w;
        *(float4*)op = cur;
    }
}

// ---------------- workspace layout (bytes), peak 147,243,264 < 155,385,856 proven (R4) ----
static const size_t WB_B   = 0;           // 48 MB weights bf16-T
static const size_t RW_B   = 50331648;    // f32 [4096][8]
static const size_t PB_B   = 50462720;    // f32 [3][8][512]
static const size_t CNT_B  = 50511872;    // i32 cnt[32] + cntpad[32]
static const size_t RIX_B  = 50512128;    // i32 [8][4096]
static const size_t SMAP_B = 50643200;    // i32 [4096][8]
static const size_t XB_B   = 50774272;    // bf16 x (4 MB)
static const size_t OC_B   = 54968576;    // bf16 [8][4096cap][512] PV out; alias HBC8 post-Wo
static const size_t QKG_B  = 88523008;    // bf16 [2t][2el][4096][512] (16 MB, per pair)
static const size_t VTG_B  = 105300224;   // bf16 [2el][16bh][128][1024] (8 MB); alias T2p in FFN
static const size_t S_B    = 113688832;   // bf16 [16][1024][1024] (32 MB); alias TC8 then MIDp

extern "C" void kernel_launch(void* const* d_in, const int* in_sizes, int n_in,
                              void* d_out, int out_size, void* d_ws, size_t ws_size,
                              hipStream_t stream) {
    const float* x      = (const float*)d_in[0];
    const float* gate_w = (const float*)d_in[1];
    const float* gate_b = (const float*)d_in[2];
    const float* ln1_s  = (const float*)d_in[3];
    const float* ln1_b  = (const float*)d_in[4];
    const float* ln2_s  = (const float*)d_in[5];
    const float* ln2_b  = (const float*)d_in[6];
    const float* wq = (const float*)d_in[7];
    const float* wk = (const float*)d_in[8];
    const float* wv = (const float*)d_in[9];
    const float* wo = (const float*)d_in[10];
    const float* bo = (const float*)d_in[14];
    const float* w1 = (const float*)d_in[15];
    const float* b1 = (const float*)d_in[16];
    const float* w2 = (const float*)d_in[17];
    const float* b2 = (const float*)d_in[18];
    float* out = (float*)d_out;

    char* ws = (char*)d_ws;
    u16*   WB   = (u16*)(ws + WB_B);
    float* RW   = (float*)(ws + RW_B);
    float* PB   = (float*)(ws + PB_B);
    int*   CNT  = (int*)(ws + CNT_B);
    int*   CNTP = CNT + 32;
    int*   RIX  = (int*)(ws + RIX_B);
    int*   SMAP = (int*)(ws + SMAP_B);
    u16*   XB   = (u16*)(ws + XB_B);
    u16*   OC8  = (u16*)(ws + OC_B);
    u16*   QKG  = (u16*)(ws + QKG_B);
    u16*   VTG  = (u16*)(ws + VTG_B);
    u16*   S    = (u16*)(ws + S_B);
    u16*   TC8  = (u16*)(ws + S_B);      // alias (post-attention)
    u16*   HBC8 = (u16*)(ws + OC_B);     // alias (post-Wo)
    u16*   MIDp = (u16*)(ws + S_B);      // alias (post-LN1)
    u16*   T2p  = (u16*)(ws + VTG_B);    // alias (FFN phase)

    // ---- setup ----
    cast_bf16_kernel<<<dim3(2048), 256, 0, stream>>>(x, XB, 4096 * 512 / 4);
    transpose_cast_kernel<<<dim3(16,16,8), dim3(32,8), 0, stream>>>(wq, WB + 0,        512,  512,  262144,  262144);
    transpose_cast_kernel<<<dim3(16,16,8), dim3(32,8), 0, stream>>>(wk, WB + 2097152,  512,  512,  262144,  262144);
    transpose_cast_kernel<<<dim3(16,16,8), dim3(32,8), 0, stream>>>(wv, WB + 4194304,  512,  512,  262144,  262144);
    transpose_cast_kernel<<<dim3(16,16,8), dim3(32,8), 0, stream>>>(wo, WB + 6291456,  512,  512,  262144,  262144);
    transpose_cast_kernel<<<dim3(64,16,8), dim3(32,8), 0, stream>>>(w1, WB + 8388608,  512,  2048, 1048576, 1048576);
    transpose_cast_kernel<<<dim3(16,64,8), dim3(32,8), 0, stream>>>(w2, WB + 16777216, 2048, 512,  1048576, 1048576);
    pack_bias_kernel<<<dim3(16,3), 256, 0, stream>>>((const float*)d_in[11], (const float*)d_in[12],
                                                     (const float*)d_in[13], PB);
    router_kernel<<<4096, 512, 0, stream>>>(x, gate_w, gate_b, RW, out + 2097152);
    build_lists_kernel<<<32, 256, 0, stream>>>(RW, RIX, SMAP, CNT, CNTP);

    const float isq = 0.08838834764831845f;  // 1/sqrt(128)

    // ---- attention in 4 pairs of experts ----
    for (int g = 0; g < 4; g++) {
        int e0 = 2 * g;
        // Q,K pair (dense): z = t*2+el
        gemm_kernel<true,false,false,false,false><<<dim3(4,32,4), 256, 0, stream>>>(
            XB, 512, 0, 0,
            WB + (size_t)e0*262144, 512, 2097152, 262144,
            QKG, 512, 4194304, 2097152,
            PB + e0*512, 4096, 512,
            2, 1.f, 512, nullptr, nullptr);
        // V pair (dense), written directly in VT layout: z = el
        gemm_kernel<true,false,false,false,true><<<dim3(4,32,2), 256, 0, stream>>>(
            XB, 512, 0, 0,
            WB + 4194304 + (size_t)e0*262144, 512, 262144, 0,
            VTG, 0, 2097152, 0,
            PB + 8192 + e0*512, 512, 0,
            1, 1.f, 512, nullptr, nullptr);
        for (int el = 0; el < 2; el++) {
            int e = e0 + el;
            // scores (compacted Q rows via ridx): z=(b,h), zo=b
            gemm_kernel<false,false,true,true,false><<<dim3(8,8,16), 256, 0, stream>>>(
                QKG + (size_t)el*2097152,           512, 0, 128,
                QKG + 4194304 + (size_t)el*2097152, 512, 524288, 128,
                S, 1024, 4194304, 1048576,
                nullptr, 0, 0,
                4, isq, 128, RIX + e*4096, CNTP + e*4);
            softmax_kernel<<<16384, 256, 0, stream>>>(S, CNT + e*4);
            // PV (compacted slot rows): z=(b,h)
            gemm_kernel<false,false,false,false,false><<<dim3(1,8,16), 256, 0, stream>>>(
                S, 1024, 4194304, 1048576,
                VTG + (size_t)el*2097152, 1024, 524288, 131072,
                OC8 + (size_t)e*2097152, 512, 524288, 128,
                nullptr, 0, 0,
                4, 1.f, 1024, nullptr, CNTP + e*4);
        }
    }

    // ---- Wo (compacted, all 8 experts) -> TC8 ----
    gemm_eb_kernel<false><<<dim3(4,256), 256, 0, stream>>>(
        OC8, 512,
        WB + 6291456, 512, 262144,
        TC8, 512,
        bo, 512,
        CNTP, 512);

    // ---- LN1 compacted -> HBC8 ----
    ln1c_kernel<<<32768, 128, 0, stream>>>(x, TC8, RIX, CNT, CNTP, ln1_s, ln1_b, HBC8);

    // ---- FFN + LN2-accumulate in 4 pairs ----
    for (int p = 0; p < 4; p++) {
        int e0 = 2 * p;
        gemm_eb_kernel<true><<<dim3(16,64), 256, 0, stream>>>(
            HBC8 + (size_t)e0*2097152, 512,
            WB + 8388608 + (size_t)e0*1048576, 512, 1048576,
            MIDp, 2048,
            b1 + e0*2048, 2048,
            CNTP + e0*4, 512);
        gemm_eb_kernel<false><<<dim3(4,64), 256, 0, stream>>>(
            MIDp, 2048,
            WB + 16777216 + (size_t)e0*1048576, 2048, 1048576,
            T2p, 512,
            b2 + e0*512, 512,
            CNTP + e0*4, 2048);
        ln2acc_pair_kernel<<<4096, 128, 0, stream>>>(
            HBC8, T2p, ln2_s, ln2_b, RW, SMAP, e0, p == 0 ? 1 : 0, out);
    }
}

// Round 6
// 852.451 us; speedup vs baseline: 2.3265x; 1.1962x over previous
//
#include <hip/hip_runtime.h>
#include <hip/hip_bf16.h>
#include <stdint.h>

using u16 = unsigned short;
typedef float floatx4 __attribute__((ext_vector_type(4)));
typedef __bf16 bfv8 __attribute__((ext_vector_type(8)));

#define AS1 __attribute__((address_space(1)))
#define AS3 __attribute__((address_space(3)))

__device__ __forceinline__ u16 f2bf_bits(float f) {
    __hip_bfloat16 h = __float2bfloat16(f);
    u16 u;
    __builtin_memcpy(&u, &h, 2);
    return u;
}
__device__ __forceinline__ float bf_bits2f(u16 u) {
    __hip_bfloat16 h;
    __builtin_memcpy(&h, &u, 2);
    return __bfloat162float(h);
}
__device__ __forceinline__ void gload_lds16(const void* g, void* l) {
    __builtin_amdgcn_global_load_lds((AS1 void*)(uintptr_t)g, (AS3 void*)l, 16, 0, 0);
}

// ---- BK=64 tile staging: 128 rows x 64 cols, XOR-swizzled chunks ----
// q = j*256+tid; LDS dst elem = q*8 (linear in lane => valid for global_load_lds);
// source chunk cg = (q&7) ^ (row&7): slot s holds global chunk s ^ (row&7).
__device__ __forceinline__ void stage64(const u16* __restrict__ Abase, long lda, const long* arow,
                                        const u16* __restrict__ Bb, long ldb, int k0, int tid,
                                        u16* Ad, u16* Bd) {
    #pragma unroll
    for (int j = 0; j < 4; ++j) {
        const int q   = j * 256 + tid;
        const int row = q >> 3;
        const int cg  = (q & 7) ^ (row & 7);
        gload_lds16(Abase + arow[j] * lda + k0 + cg * 8, Ad + q * 8);
        gload_lds16(Bb + (long)row * ldb + k0 + cg * 8, Bd + q * 8);
    }
}

// ---- BK=64 compute: two k-steps of 32, 32 MFMA per wave ----
__device__ __forceinline__ void compute64(const u16* Ab, const u16* Bb, int wy, int wx,
                                          int quad, int mrow, floatx4 acc[4][4]) {
    #pragma unroll
    for (int kk = 0; kk < 2; ++kk) {
        bfv8 af[4], bf[4];
        #pragma unroll
        for (int mi = 0; mi < 4; mi++) {
            const int r = wy * 64 + mi * 16 + mrow;
            const int slot = (kk * 4 + quad) ^ (r & 7);
            af[mi] = *(const bfv8*)&Ab[r * 64 + slot * 8];
        }
        #pragma unroll
        for (int ni = 0; ni < 4; ni++) {
            const int r = wx * 64 + ni * 16 + mrow;
            const int slot = (kk * 4 + quad) ^ (r & 7);
            bf[ni] = *(const bfv8*)&Bb[r * 64 + slot * 8];
        }
        #pragma unroll
        for (int mi = 0; mi < 4; mi++)
            #pragma unroll
            for (int ni = 0; ni < 4; ni++)
                acc[mi][ni] = __builtin_amdgcn_mfma_f32_16x16x32_bf16(af[mi], bf[ni], acc[mi][ni], 0, 0, 0);
    }
}

// ---------------- cast fp32 -> bf16 ----------------
__global__ void cast_bf16_kernel(const float* __restrict__ in, u16* __restrict__ out, int n4) {
    int i = blockIdx.x * blockDim.x + threadIdx.x;
    if (i >= n4) return;
    float4 v = ((const float4*)in)[i];
    ushort4 o;
    o.x = f2bf_bits(v.x); o.y = f2bf_bits(v.y); o.z = f2bf_bits(v.z); o.w = f2bf_bits(v.w);
    ((ushort4*)out)[i] = o;
}

// ---------------- transpose+cast fp32 [z][R][C] -> bf16 [z][C][R] ----------------
__global__ void transpose_cast_kernel(const float* __restrict__ src, u16* __restrict__ dst,
                                      int R, int C, long sSrc, long sDst) {
    __shared__ float tile[32][33];
    const float* s = src + (long)blockIdx.z * sSrc;
    u16* d = dst + (long)blockIdx.z * sDst;
    int c0 = blockIdx.x * 32, r0 = blockIdx.y * 32;
    int tx = threadIdx.x, ty = threadIdx.y;
    #pragma unroll
    for (int i = 0; i < 4; i++)
        tile[ty + 8*i][tx] = s[(long)(r0 + ty + 8*i) * C + c0 + tx];
    __syncthreads();
    #pragma unroll
    for (int i = 0; i < 4; i++)
        d[(long)(c0 + ty + 8*i) * R + r0 + tx] = f2bf_bits(tile[tx][ty + 8*i]);
}

// ---------------- pack bq/bk/bv -> PB[3][8][512] ----------------
__global__ void pack_bias_kernel(const float* __restrict__ bq, const float* __restrict__ bk,
                                 const float* __restrict__ bv, float* __restrict__ pb) {
    int i = blockIdx.x * 256 + threadIdx.x;
    const float* s = blockIdx.y == 0 ? bq : (blockIdx.y == 1 ? bk : bv);
    pb[blockIdx.y * 4096 + i] = s[i];
}

// ---------------- router ----------------
__global__ __launch_bounds__(512)
void router_kernel(const float* __restrict__ x, const float* __restrict__ gw,
                   const float* __restrict__ gb, float* __restrict__ rw,
                   float* __restrict__ logits_out) {
    int row = blockIdx.x;
    int w = threadIdx.x >> 6;
    int lane = threadIdx.x & 63;
    const float* xr = x + (long)row * 512;
    float sum = 0.f;
    #pragma unroll
    for (int i = 0; i < 8; i++) {
        int d = lane + 64 * i;
        sum += xr[d] * gw[d * 8 + w];
    }
    #pragma unroll
    for (int o = 32; o; o >>= 1) sum += __shfl_down(sum, o, 64);
    __shared__ float lg[8];
    if (lane == 0) lg[w] = sum + gb[w];
    __syncthreads();
    if (threadIdx.x == 0) {
        float l[8];
        #pragma unroll
        for (int e = 0; e < 8; e++) l[e] = lg[e];
        int i1 = 0;
        for (int e = 1; e < 8; e++) if (l[e] > l[i1]) i1 = e;
        int i2 = -1;
        for (int e = 0; e < 8; e++) { if (e == i1) continue; if (i2 < 0 || l[e] > l[i2]) i2 = e; }
        for (int e = 0; e < 8; e++) {
            float v = (e == i1 || e == i2) ? (l[e] > 0.f ? l[e] : 0.f) : 0.f;
            float r = 0.f, mem = v;
            #pragma unroll
            for (int lvl = 0; lvl < 4; lvl++) {
                float thr = 4.0f / (float)(1 << lvl);
                if (mem >= thr) { r += thr; mem -= thr; }
            }
            rw[(long)row * 8 + e] = r;
            logits_out[(long)row * 8 + e] = l[e];
        }
    }
}

// ---------------- build per-(e,b) compacted row lists ----------------
__global__ __launch_bounds__(256)
void build_lists_kernel(const float* __restrict__ rw, int* __restrict__ rix,
                        int* __restrict__ smap, int* __restrict__ cnt, int* __restrict__ cntpad) {
    int e = blockIdx.x >> 2, b = blockIdx.x & 3;
    int t = threadIdx.x;
    __shared__ int pc[256];
    __shared__ int totsh;
    int r0 = b * 1024 + t * 4;
    int f[4];
    int c = 0;
    #pragma unroll
    for (int i = 0; i < 4; i++) {
        f[i] = (rw[(long)(r0 + i) * 8 + e] != 0.f) ? 1 : 0;
        c += f[i];
    }
    pc[t] = c;
    __syncthreads();
    if (t == 0) {
        int run = 0;
        for (int i = 0; i < 256; i++) { int v = pc[i]; pc[i] = run; run += v; }
        totsh = run;
    }
    __syncthreads();
    int slot = pc[t];
    #pragma unroll
    for (int i = 0; i < 4; i++) {
        int r = r0 + i;
        if (f[i]) {
            rix[e * 4096 + b * 1024 + slot] = r;
            smap[(long)r * 8 + e] = b * 1024 + slot;
            slot++;
        } else {
            smap[(long)r * 8 + e] = -1;
        }
    }
    int tot = totsh;
    for (int s = tot + t; s < 1024; s += 256) rix[e * 4096 + b * 1024 + s] = b * 1024;
    if (t == 0) {
        cnt[blockIdx.x] = tot;
        cntpad[blockIdx.x] = (tot + 127) & ~127;
    }
}

// ---------------- GEMM: C[M,N] = A[M,K] @ Bt[N,K]^T, dbuf BK=64 ----------------
template<bool BIAS, bool RELU, bool SCALE, bool IDX, bool TRANSC>
__global__ __launch_bounds__(256)
void gemm_kernel(const u16* __restrict__ A, int lda, long sAo, long sAi,
                 const u16* __restrict__ B, int ldb, long sBo, long sBi,
                 u16* __restrict__ C, int ldc, long sCo, long sCi,
                 const float* __restrict__ bias, long sBiasO, long sBiasI,
                 int zdiv, float alpha, int K,
                 const int* __restrict__ ridx, const int* __restrict__ mcnt) {
    __shared__ __align__(16) u16 As[2][128 * 64];
    __shared__ __align__(16) u16 Bs[2][128 * 64];
    const int z = blockIdx.z;
    const int zo = z / zdiv, zi = z % zdiv;
    if (mcnt && (int)blockIdx.y * 128 >= mcnt[zo]) return;

    const u16* Abase = A + zo * sAo + zi * sAi;
    const u16* Bb = B + zo * sBo + zi * sBi + (long)blockIdx.x * 128 * ldb;

    const int tid = threadIdx.x;
    const int w = tid >> 6, lane = tid & 63;
    const int wy = w >> 1, wx = w & 1;
    const int quad = lane >> 4, mrow = lane & 15;

    long arow[4];
    #pragma unroll
    for (int j = 0; j < 4; ++j) {
        const int row = (j * 256 + tid) >> 3;
        if (IDX) arow[j] = ridx[zo * 1024 + blockIdx.y * 128 + row];
        else     arow[j] = (long)blockIdx.y * 128 + row;
    }

    floatx4 acc[4][4];
    #pragma unroll
    for (int i = 0; i < 4; i++)
        #pragma unroll
        for (int j = 0; j < 4; j++)
            acc[i][j] = floatx4{0.f, 0.f, 0.f, 0.f};

    const int nk = K >> 6;
    stage64(Abase, lda, arow, Bb, ldb, 0, tid, As[0], Bs[0]);
    for (int it = 0; it < nk; ++it) {
        const int cur = it & 1;
        __syncthreads();                       // drains vmcnt -> buf[cur] ready
        if (it + 1 < nk)
            stage64(Abase, lda, arow, Bb, ldb, (it + 1) << 6, tid, As[1 - cur], Bs[1 - cur]);
        compute64(As[cur], Bs[cur], wy, wx, quad, mrow, acc);
    }

    const float* biasb = BIAS ? (bias + zo * sBiasO + zi * sBiasI + (long)blockIdx.x * 128) : nullptr;
    if constexpr (TRANSC) {
        u16* Cb = C + zo * sCo + zi * sCi;
        #pragma unroll
        for (int ni = 0; ni < 4; ni++) {
            const int colt = wx * 64 + ni * 16 + mrow;
            const int n = blockIdx.x * 128 + colt;
            float bv = BIAS ? biasb[colt] : 0.f;
            #pragma unroll
            for (int mi = 0; mi < 4; mi++) {
                #pragma unroll
                for (int r = 0; r < 4; r++) {
                    const int m = blockIdx.y * 128 + wy * 64 + mi * 16 + quad * 4 + r;
                    float v = acc[mi][ni][r];
                    if (BIAS) v += bv;
                    long addr = ((long)(((m >> 10) << 2) + (n >> 7)) * 128 + (n & 127)) * 1024 + (m & 1023);
                    Cb[addr] = f2bf_bits(v);
                }
            }
        }
    } else {
        u16* Cb = C + zo * sCo + zi * sCi + (long)blockIdx.y * 128 * ldc + (long)blockIdx.x * 128;
        #pragma unroll
        for (int ni = 0; ni < 4; ni++) {
            const int col = wx * 64 + ni * 16 + mrow;
            float bv = 0.f;
            if (BIAS) bv = biasb[col];
            #pragma unroll
            for (int mi = 0; mi < 4; mi++) {
                #pragma unroll
                for (int r = 0; r < 4; r++) {
                    const int row = wy * 64 + mi * 16 + quad * 4 + r;
                    float v = acc[mi][ni][r];
                    if (SCALE) v *= alpha;
                    if (BIAS) v += bv;
                    if (RELU) v = fmaxf(v, 0.f);
                    Cb[(long)row * ldc + col] = f2bf_bits(v);
                }
            }
        }
    }
}

// ---------------- compacted (e,b,mtile) GEMM for Wo / FFN1 / FFN2, dbuf BK=64 ----------------
template<bool RELU>
__global__ __launch_bounds__(256)
void gemm_eb_kernel(const u16* __restrict__ A, int lda,
                    const u16* __restrict__ B, int ldb, long sBe,
                    u16* __restrict__ C, int ldc,
                    const float* __restrict__ bias, long sBiasE,
                    const int* __restrict__ cntp, int K) {
    __shared__ __align__(16) u16 As[2][128 * 64];
    __shared__ __align__(16) u16 Bs[2][128 * 64];
    const int y = blockIdx.y;
    const int mt = y & 7, b = (y >> 3) & 3, el = y >> 5;
    if (mt * 128 >= cntp[el * 4 + b]) return;
    const long rbase = (long)(((el * 4 + b) << 10) + mt * 128);
    const u16* Ab = A + rbase * lda;
    const u16* Bb = B + (long)el * sBe + (long)blockIdx.x * 128 * ldb;

    const int tid = threadIdx.x;
    const int w = tid >> 6, lane = tid & 63;
    const int wy = w >> 1, wx = w & 1;
    const int quad = lane >> 4, mrow = lane & 15;

    long arow[4];
    #pragma unroll
    for (int j = 0; j < 4; ++j) arow[j] = (j * 256 + tid) >> 3;

    floatx4 acc[4][4];
    #pragma unroll
    for (int i = 0; i < 4; i++)
        #pragma unroll
        for (int j = 0; j < 4; j++)
            acc[i][j] = floatx4{0.f, 0.f, 0.f, 0.f};

    const int nk = K >> 6;
    stage64(Ab, lda, arow, Bb, ldb, 0, tid, As[0], Bs[0]);
    for (int it = 0; it < nk; ++it) {
        const int cur = it & 1;
        __syncthreads();
        if (it + 1 < nk)
            stage64(Ab, lda, arow, Bb, ldb, (it + 1) << 6, tid, As[1 - cur], Bs[1 - cur]);
        compute64(As[cur], Bs[cur], wy, wx, quad, mrow, acc);
    }

    u16* Cb = C + rbase * ldc + (long)blockIdx.x * 128;
    const float* biasb = bias + el * sBiasE + (long)blockIdx.x * 128;
    #pragma unroll
    for (int ni = 0; ni < 4; ni++) {
        const int col = wx * 64 + ni * 16 + mrow;
        float bv = biasb[col];
        #pragma unroll
        for (int mi = 0; mi < 4; mi++) {
            #pragma unroll
            for (int r = 0; r < 4; r++) {
                const int row = wy * 64 + mi * 16 + quad * 4 + r;
                float v = acc[mi][ni][r] + bv;
                if (RELU) v = fmaxf(v, 0.f);
                Cb[(long)row * ldc + col] = f2bf_bits(v);
            }
        }
    }
}

// ---------------- softmax over rows of 1024, compacted rows only ----------------
__global__ __launch_bounds__(256)
void softmax_kernel(u16* __restrict__ S, const int* __restrict__ cnt) {
    int idx = blockIdx.x;
    int slot = idx & 1023;
    int b = idx >> 12;
    if (slot >= cnt[b]) return;
    u16* p = S + (long)idx * 1024;
    int t = threadIdx.x, w = t >> 6, lane = t & 63;
    float v[4];
    float mx = -1e30f;
    #pragma unroll
    for (int i = 0; i < 4; i++) {
        v[i] = bf_bits2f(p[t + 256 * i]);
        mx = fmaxf(mx, v[i]);
    }
    #pragma unroll
    for (int o = 32; o; o >>= 1) mx = fmaxf(mx, __shfl_down(mx, o, 64));
    __shared__ float red[8];
    if (lane == 0) red[w] = mx;
    __syncthreads();
    mx = fmaxf(fmaxf(red[0], red[1]), fmaxf(red[2], red[3]));
    float sum = 0.f;
    #pragma unroll
    for (int i = 0; i < 4; i++) { v[i] = __expf(v[i] - mx); sum += v[i]; }
    #pragma unroll
    for (int o = 32; o; o >>= 1) sum += __shfl_down(sum, o, 64);
    if (lane == 0) red[4 + w] = sum;
    __syncthreads();
    float inv = 1.f / (red[4] + red[5] + red[6] + red[7]);
    #pragma unroll
    for (int i = 0; i < 4; i++) p[t + 256 * i] = f2bf_bits(v[i] * inv);
}

// ---------------- LN1 on compacted rows ----------------
__global__ __launch_bounds__(128)
void ln1c_kernel(const float* __restrict__ x, const u16* __restrict__ t,
                 const int* __restrict__ rix, const int* __restrict__ cnt,
                 const int* __restrict__ cntpad,
                 const float* __restrict__ s_all, const float* __restrict__ b_all,
                 u16* __restrict__ hb) {
    int blk = blockIdx.x;
    int e = blk >> 12, b = (blk >> 10) & 3, sl = blk & 1023;
    int idx = e * 4 + b;
    if (sl >= cntpad[idx]) return;
    long rowc = (long)e * 4096 + b * 1024 + sl;
    int tid = threadIdx.x, w = tid >> 6, lane = tid & 63;
    if (sl >= cnt[idx]) {
        *(ushort4*)(hb + rowc * 512 + tid * 4) = make_ushort4(0, 0, 0, 0);
        return;
    }
    int r = rix[e * 4096 + b * 1024 + sl];
    float4 xv = *(const float4*)(x + (long)r * 512 + tid * 4);
    ushort4 tu = *(const ushort4*)(t + rowc * 512 + tid * 4);
    float v[4] = {xv.x + bf_bits2f(tu.x), xv.y + bf_bits2f(tu.y),
                  xv.z + bf_bits2f(tu.z), xv.w + bf_bits2f(tu.w)};
    float sum = v[0] + v[1] + v[2] + v[3];
    #pragma unroll
    for (int o = 32; o; o >>= 1) sum += __shfl_down(sum, o, 64);
    __shared__ float sh[4];
    if (lane == 0) sh[w] = sum;
    __syncthreads();
    float mu = (sh[0] + sh[1]) * (1.f / 512.f);
    float sq = 0.f;
    #pragma unroll
    for (int j = 0; j < 4; j++) { float d = v[j] - mu; sq += d * d; }
    #pragma unroll
    for (int o = 32; o; o >>= 1) sq += __shfl_down(sq, o, 64);
    if (lane == 0) sh[2 + w] = sq;
    __syncthreads();
    float inv = 1.f / sqrtf((sh[2] + sh[3]) * (1.f / 512.f) + 1e-5f);
    float4 sv = *(const float4*)(s_all + e * 512 + tid * 4);
    float4 bv = *(const float4*)(b_all + e * 512 + tid * 4);
    ushort4 ub;
    ub.x = f2bf_bits((v[0] - mu) * inv * sv.x + bv.x);
    ub.y = f2bf_bits((v[1] - mu) * inv * sv.y + bv.y);
    ub.z = f2bf_bits((v[2] - mu) * inv * sv.z + bv.z);
    ub.w = f2bf_bits((v[3] - mu) * inv * sv.w + bv.w);
    *(ushort4*)(hb + rowc * 512 + tid * 4) = ub;
}

// ---------------- LN2 + weighted accumulate for a pair of experts ----------------
__global__ __launch_bounds__(128)
void ln2acc_pair_kernel(const u16* __restrict__ hb, const u16* __restrict__ t2,
                        const float* __restrict__ s_all, const float* __restrict__ b_all,
                        const float* __restrict__ rw, const int* __restrict__ smap,
                        int e0, int init, float* __restrict__ out) {
    long r = blockIdx.x;
    int tid = threadIdx.x, w = tid >> 6, lane = tid & 63;
    __shared__ float sh[4];
    float4 acc = make_float4(0.f, 0.f, 0.f, 0.f);
    for (int el = 0; el < 2; el++) {
        int e = e0 + el;
        int sl = smap[r * 8 + e];
        if (sl >= 0) {
            float wgt = rw[r * 8 + e];
            long rh = (long)e * 4096 + sl;
            long rt = (long)el * 4096 + sl;
            ushort4 hu = *(const ushort4*)(hb + rh * 512 + tid * 4);
            ushort4 fu = *(const ushort4*)(t2 + rt * 512 + tid * 4);
            float v[4] = {bf_bits2f(hu.x) + bf_bits2f(fu.x), bf_bits2f(hu.y) + bf_bits2f(fu.y),
                          bf_bits2f(hu.z) + bf_bits2f(fu.z), bf_bits2f(hu.w) + bf_bits2f(fu.w)};
            float sum = v[0] + v[1] + v[2] + v[3];
            #pragma unroll
            for (int o = 32; o; o >>= 1) sum += __shfl_down(sum, o, 64);
            if (lane == 0) sh[w] = sum;
            __syncthreads();
            float mu = (sh[0] + sh[1]) * (1.f / 512.f);
            float sq = 0.f;
            #pragma unroll
            for (int j = 0; j < 4; j++) { float d = v[j] - mu; sq += d * d; }
            #pragma unroll
            for (int o = 32; o; o >>= 1) sq += __shfl_down(sq, o, 64);
            if (lane == 0) sh[2 + w] = sq;
            __syncthreads();
            float inv = 1.f / sqrtf((sh[2] + sh[3]) * (1.f / 512.f) + 1e-5f);
            float4 sv = *(const float4*)(s_all + e * 512 + tid * 4);
            float4 bv = *(const float4*)(b_all + e * 512 + tid * 4);
            acc.x += wgt * ((v[0] - mu) * inv * sv.x + bv.x);
            acc.y += wgt * ((v[1] - mu) * inv * sv.y + bv.y);
            acc.z += wgt * ((v[2] - mu) * inv * sv.z + bv.z);
            acc.w += wgt * ((v[3] - mu) * inv * sv.w + bv.w);
            __syncthreads();
        }
    }
    float* op = out + r * 512 + tid * 4;
    if (init) {
        *(float4*)op = acc;
    } else {
        float4 cur = *(float4*)op;
        cur.x += acc.x; cur.y += acc.y; cur.z += acc.z; cur.w += acc.w;
        *(float4*)op = cur;
    }
}

// ---------------- workspace layout (bytes), peak 147,243,264 (proven R5) ----
static const size_t WB_B   = 0;
static const size_t RW_B   = 50331648;
static const size_t PB_B   = 50462720;
static const size_t CNT_B  = 50511872;
static const size_t RIX_B  = 50512128;
static const size_t SMAP_B = 50643200;
static const size_t XB_B   = 50774272;
static const size_t OC_B   = 54968576;
static const size_t QKG_B  = 88523008;
static const size_t VTG_B  = 105300224;
static const size_t S_B    = 113688832;

extern "C" void kernel_launch(void* const* d_in, const int* in_sizes, int n_in,
                              void* d_out, int out_size, void* d_ws, size_t ws_size,
                              hipStream_t stream) {
    const float* x      = (const float*)d_in[0];
    const float* gate_w = (const float*)d_in[1];
    const float* gate_b = (const float*)d_in[2];
    const float* ln1_s  = (const float*)d_in[3];
    const float* ln1_b  = (const float*)d_in[4];
    const float* ln2_s  = (const float*)d_in[5];
    const float* ln2_b  = (const float*)d_in[6];
    const float* wq = (const float*)d_in[7];
    const float* wk = (const float*)d_in[8];
    const float* wv = (const float*)d_in[9];
    const float* wo = (const float*)d_in[10];
    const float* bo = (const float*)d_in[14];
    const float* w1 = (const float*)d_in[15];
    const float* b1 = (const float*)d_in[16];
    const float* w2 = (const float*)d_in[17];
    const float* b2 = (const float*)d_in[18];
    float* out = (float*)d_out;

    char* ws = (char*)d_ws;
    u16*   WB   = (u16*)(ws + WB_B);
    float* RW   = (float*)(ws + RW_B);
    float* PB   = (float*)(ws + PB_B);
    int*   CNT  = (int*)(ws + CNT_B);
    int*   CNTP = CNT + 32;
    int*   RIX  = (int*)(ws + RIX_B);
    int*   SMAP = (int*)(ws + SMAP_B);
    u16*   XB   = (u16*)(ws + XB_B);
    u16*   OC8  = (u16*)(ws + OC_B);
    u16*   QKG  = (u16*)(ws + QKG_B);
    u16*   VTG  = (u16*)(ws + VTG_B);
    u16*   S    = (u16*)(ws + S_B);
    u16*   TC8  = (u16*)(ws + S_B);      // alias (post-attention)
    u16*   HBC8 = (u16*)(ws + OC_B);     // alias (post-Wo)
    u16*   MIDp = (u16*)(ws + S_B);      // alias (post-LN1)
    u16*   T2p  = (u16*)(ws + VTG_B);    // alias (FFN phase)

    // ---- setup ----
    cast_bf16_kernel<<<dim3(2048), 256, 0, stream>>>(x, XB, 4096 * 512 / 4);
    transpose_cast_kernel<<<dim3(16,16,8), dim3(32,8), 0, stream>>>(wq, WB + 0,        512,  512,  262144,  262144);
    transpose_cast_kernel<<<dim3(16,16,8), dim3(32,8), 0, stream>>>(wk, WB + 2097152,  512,  512,  262144,  262144);
    transpose_cast_kernel<<<dim3(16,16,8), dim3(32,8), 0, stream>>>(wv, WB + 4194304,  512,  512,  262144,  262144);
    transpose_cast_kernel<<<dim3(16,16,8), dim3(32,8), 0, stream>>>(wo, WB + 6291456,  512,  512,  262144,  262144);
    transpose_cast_kernel<<<dim3(64,16,8), dim3(32,8), 0, stream>>>(w1, WB + 8388608,  512,  2048, 1048576, 1048576);
    transpose_cast_kernel<<<dim3(16,64,8), dim3(32,8), 0, stream>>>(w2, WB + 16777216, 2048, 512,  1048576, 1048576);
    pack_bias_kernel<<<dim3(16,3), 256, 0, stream>>>((const float*)d_in[11], (const float*)d_in[12],
                                                     (const float*)d_in[13], PB);
    router_kernel<<<4096, 512, 0, stream>>>(x, gate_w, gate_b, RW, out + 2097152);
    build_lists_kernel<<<32, 256, 0, stream>>>(RW, RIX, SMAP, CNT, CNTP);

    const float isq = 0.08838834764831845f;  // 1/sqrt(128)

    // ---- attention in 4 pairs of experts ----
    for (int g = 0; g < 4; g++) {
        int e0 = 2 * g;
        // Q,K pair (dense): z = t*2+el
        gemm_kernel<true,false,false,false,false><<<dim3(4,32,4), 256, 0, stream>>>(
            XB, 512, 0, 0,
            WB + (size_t)e0*262144, 512, 2097152, 262144,
            QKG, 512, 4194304, 2097152,
            PB + e0*512, 4096, 512,
            2, 1.f, 512, nullptr, nullptr);
        // V pair (dense), direct-transposed C: z = el
        gemm_kernel<true,false,false,false,true><<<dim3(4,32,2), 256, 0, stream>>>(
            XB, 512, 0, 0,
            WB + 4194304 + (size_t)e0*262144, 512, 262144, 0,
            VTG, 0, 2097152, 0,
            PB + 8192 + e0*512, 512, 0,
            1, 1.f, 512, nullptr, nullptr);
        for (int el = 0; el < 2; el++) {
            int e = e0 + el;
            // scores (compacted Q rows): z=(b,h), zo=b
            gemm_kernel<false,false,true,true,false><<<dim3(8,8,16), 256, 0, stream>>>(
                QKG + (size_t)el*2097152,           512, 0, 128,
                QKG + 4194304 + (size_t)el*2097152, 512, 524288, 128,
                S, 1024, 4194304, 1048576,
                nullptr, 0, 0,
                4, isq, 128, RIX + e*4096, CNTP + e*4);
            softmax_kernel<<<16384, 256, 0, stream>>>(S, CNT + e*4);
            // PV (compacted slot rows): z=(b,h)
            gemm_kernel<false,false,false,false,false><<<dim3(1,8,16), 256, 0, stream>>>(
                S, 1024, 4194304, 1048576,
                VTG + (size_t)el*2097152, 1024, 524288, 131072,
                OC8 + (size_t)e*2097152, 512, 524288, 128,
                nullptr, 0, 0,
                4, 1.f, 1024, nullptr, CNTP + e*4);
        }
    }

    // ---- Wo (compacted, all 8 experts) -> TC8 ----
    gemm_eb_kernel<false><<<dim3(4,256), 256, 0, stream>>>(
        OC8, 512,
        WB + 6291456, 512, 262144,
        TC8, 512,
        bo, 512,
        CNTP, 512);

    // ---- LN1 compacted -> HBC8 ----
    ln1c_kernel<<<32768, 128, 0, stream>>>(x, TC8, RIX, CNT, CNTP, ln1_s, ln1_b, HBC8);

    // ---- FFN + LN2-accumulate in 4 pairs ----
    for (int p = 0; p < 4; p++) {
        int e0 = 2 * p;
        gemm_eb_kernel<true><<<dim3(16,64), 256, 0, stream>>>(
            HBC8 + (size_t)e0*2097152, 512,
            WB + 8388608 + (size_t)e0*1048576, 512, 1048576,
            MIDp, 2048,
            b1 + e0*2048, 2048,
            CNTP + e0*4, 512);
        gemm_eb_kernel<false><<<dim3(4,64), 256, 0, stream>>>(
            MIDp, 2048,
            WB + 16777216 + (size_t)e0*1048576, 2048, 1048576,
            T2p, 512,
            b2 + e0*512, 512,
            CNTP + e0*4, 2048);
        ln2acc_pair_kernel<<<4096, 128, 0, stream>>>(
            HBC8, T2p, ln2_s, ln2_b, RW, SMAP, e0, p == 0 ? 1 : 0, out);
    }
}

// Round 7
// 501.215 us; speedup vs baseline: 3.9569x; 1.7008x over previous
//
#include <hip/hip_runtime.h>
#include <hip/hip_bf16.h>
#include <stdint.h>

using u16 = unsigned short;
typedef float floatx4 __attribute__((ext_vector_type(4)));
typedef __bf16 bfv8 __attribute__((ext_vector_type(8)));

#define AS1 __attribute__((address_space(1)))
#define AS3 __attribute__((address_space(3)))

__device__ __forceinline__ u16 f2bf_bits(float f) {
    __hip_bfloat16 h = __float2bfloat16(f);
    u16 u;
    __builtin_memcpy(&u, &h, 2);
    return u;
}
__device__ __forceinline__ float bf_bits2f(u16 u) {
    __hip_bfloat16 h;
    __builtin_memcpy(&h, &u, 2);
    return __bfloat162float(h);
}
__device__ __forceinline__ void gload_lds16(const void* g, void* l) {
    __builtin_amdgcn_global_load_lds((AS1 void*)(uintptr_t)g, (AS3 void*)l, 16, 0, 0);
}

// ---- BK=64 tile staging (dbuf), XOR-swizzled chunks (R6-proven) ----
__device__ __forceinline__ void stage64(const u16* __restrict__ Abase, long lda, const long* arow,
                                        const u16* __restrict__ Bb, long ldb, int k0, int tid,
                                        u16* Ad, u16* Bd) {
    #pragma unroll
    for (int j = 0; j < 4; ++j) {
        const int q   = j * 256 + tid;
        const int row = q >> 3;
        const int cg  = (q & 7) ^ (row & 7);
        gload_lds16(Abase + arow[j] * lda + k0 + cg * 8, Ad + q * 8);
        gload_lds16(Bb + (long)row * ldb + k0 + cg * 8, Bd + q * 8);
    }
}
__device__ __forceinline__ void compute64(const u16* Ab, const u16* Bb, int wy, int wx,
                                          int quad, int mrow, floatx4 acc[4][4]) {
    #pragma unroll
    for (int kk = 0; kk < 2; ++kk) {
        bfv8 af[4], bf[4];
        #pragma unroll
        for (int mi = 0; mi < 4; mi++) {
            const int r = wy * 64 + mi * 16 + mrow;
            const int slot = (kk * 4 + quad) ^ (r & 7);
            af[mi] = *(const bfv8*)&Ab[r * 64 + slot * 8];
        }
        #pragma unroll
        for (int ni = 0; ni < 4; ni++) {
            const int r = wx * 64 + ni * 16 + mrow;
            const int slot = (kk * 4 + quad) ^ (r & 7);
            bf[ni] = *(const bfv8*)&Bb[r * 64 + slot * 8];
        }
        #pragma unroll
        for (int mi = 0; mi < 4; mi++)
            #pragma unroll
            for (int ni = 0; ni < 4; ni++)
                acc[mi][ni] = __builtin_amdgcn_mfma_f32_16x16x32_bf16(af[mi], bf[ni], acc[mi][ni], 0, 0, 0);
    }
}

// ---------------- cast fp32 -> bf16 ----------------
__global__ void cast_bf16_kernel(const float* __restrict__ in, u16* __restrict__ out, int n4) {
    int i = blockIdx.x * blockDim.x + threadIdx.x;
    if (i >= n4) return;
    float4 v = ((const float4*)in)[i];
    ushort4 o;
    o.x = f2bf_bits(v.x); o.y = f2bf_bits(v.y); o.z = f2bf_bits(v.z); o.w = f2bf_bits(v.w);
    ((ushort4*)out)[i] = o;
}

// ---------------- transpose+cast fp32 [z][R][C] -> bf16 [z][C][R] ----------------
__global__ void transpose_cast_kernel(const float* __restrict__ src, u16* __restrict__ dst,
                                      int R, int C, long sSrc, long sDst) {
    __shared__ float tile[32][33];
    const float* s = src + (long)blockIdx.z * sSrc;
    u16* d = dst + (long)blockIdx.z * sDst;
    int c0 = blockIdx.x * 32, r0 = blockIdx.y * 32;
    int tx = threadIdx.x, ty = threadIdx.y;
    #pragma unroll
    for (int i = 0; i < 4; i++)
        tile[ty + 8*i][tx] = s[(long)(r0 + ty + 8*i) * C + c0 + tx];
    __syncthreads();
    #pragma unroll
    for (int i = 0; i < 4; i++)
        d[(long)(c0 + ty + 8*i) * R + r0 + tx] = f2bf_bits(tile[tx][ty + 8*i]);
}

// ---------------- pack bq/bk/bv -> PB[3][8][512] ----------------
__global__ void pack_bias_kernel(const float* __restrict__ bq, const float* __restrict__ bk,
                                 const float* __restrict__ bv, float* __restrict__ pb) {
    int i = blockIdx.x * 256 + threadIdx.x;
    const float* s = blockIdx.y == 0 ? bq : (blockIdx.y == 1 ? bk : bv);
    pb[blockIdx.y * 4096 + i] = s[i];
}

// ---------------- router ----------------
__global__ __launch_bounds__(512)
void router_kernel(const float* __restrict__ x, const float* __restrict__ gw,
                   const float* __restrict__ gb, float* __restrict__ rw,
                   float* __restrict__ logits_out) {
    int row = blockIdx.x;
    int w = threadIdx.x >> 6;
    int lane = threadIdx.x & 63;
    const float* xr = x + (long)row * 512;
    float sum = 0.f;
    #pragma unroll
    for (int i = 0; i < 8; i++) {
        int d = lane + 64 * i;
        sum += xr[d] * gw[d * 8 + w];
    }
    #pragma unroll
    for (int o = 32; o; o >>= 1) sum += __shfl_down(sum, o, 64);
    __shared__ float lg[8];
    if (lane == 0) lg[w] = sum + gb[w];
    __syncthreads();
    if (threadIdx.x == 0) {
        float l[8];
        #pragma unroll
        for (int e = 0; e < 8; e++) l[e] = lg[e];
        int i1 = 0;
        for (int e = 1; e < 8; e++) if (l[e] > l[i1]) i1 = e;
        int i2 = -1;
        for (int e = 0; e < 8; e++) { if (e == i1) continue; if (i2 < 0 || l[e] > l[i2]) i2 = e; }
        for (int e = 0; e < 8; e++) {
            float v = (e == i1 || e == i2) ? (l[e] > 0.f ? l[e] : 0.f) : 0.f;
            float r = 0.f, mem = v;
            #pragma unroll
            for (int lvl = 0; lvl < 4; lvl++) {
                float thr = 4.0f / (float)(1 << lvl);
                if (mem >= thr) { r += thr; mem -= thr; }
            }
            rw[(long)row * 8 + e] = r;
            logits_out[(long)row * 8 + e] = l[e];
        }
    }
}

// ---------------- build packed row space: per b, experts packed back-to-back ----------------
// grid 4 (b), 256 threads. Outputs:
//  PRIX[b][3072]  packed slot -> global row (pad -> b*1024)
//  ACT [b][3072]  1 if real row
//  SMAP[r][8]     global row,e -> packed slot (or -1)
//  TMAP[b][32]    packed tile -> expert
//  TT[b] tiles, PT[b] = TT*128
__global__ __launch_bounds__(256)
void build_lists_kernel(const float* __restrict__ rw, int* __restrict__ prix,
                        int* __restrict__ act, int* __restrict__ smap,
                        int* __restrict__ tmap, int* __restrict__ tt, int* __restrict__ pt) {
    int b = blockIdx.x;
    int t = threadIdx.x, wv = t >> 6, lane = t & 63;
    __shared__ int wsum[4];
    __shared__ int base_sh;
    if (t == 0) base_sh = 0;
    __syncthreads();
    for (int e = 0; e < 8; e++) {
        int r0 = b * 1024 + t * 4;
        int f[4], c = 0;
        #pragma unroll
        for (int i = 0; i < 4; i++) {
            f[i] = (rw[(long)(r0 + i) * 8 + e] != 0.f) ? 1 : 0;
            c += f[i];
        }
        int incl = c;
        #pragma unroll
        for (int o = 1; o < 64; o <<= 1) {
            int n = __shfl_up(incl, o, 64);
            if (lane >= o) incl += n;
        }
        if (lane == 63) wsum[wv] = incl;
        __syncthreads();
        int woff = 0;
        #pragma unroll
        for (int k = 0; k < 4; k++) if (k < wv) woff += wsum[k];
        int tot = wsum[0] + wsum[1] + wsum[2] + wsum[3];
        int excl = incl - c + woff;
        int base = base_sh;
        int slot = excl;
        #pragma unroll
        for (int i = 0; i < 4; i++) {
            int r = r0 + i;
            if (f[i]) {
                int ps = base + slot;
                prix[b * 3072 + ps] = r;
                act[b * 3072 + ps] = 1;
                smap[(long)r * 8 + e] = ps;
                slot++;
            } else {
                smap[(long)r * 8 + e] = -1;
            }
        }
        int pad = (tot + 127) & ~127;
        for (int s = tot + t; s < pad; s += 256) {
            prix[b * 3072 + base + s] = b * 1024;
            act[b * 3072 + base + s] = 0;
        }
        for (int k = t; k < (pad >> 7); k += 256)
            tmap[b * 32 + (base >> 7) + k] = e;
        __syncthreads();
        if (t == 0) base_sh = base + pad;
        __syncthreads();
    }
    if (t == 0) {
        tt[b] = base_sh >> 7;
        pt[b] = base_sh;
    }
}

// ---------------- dense GEMM (QKV projections): C = A @ Bt^T + bias ----------------
template<bool TRANSC>
__global__ __launch_bounds__(256)
void gemm_dense_kernel(const u16* __restrict__ A,
                       const u16* __restrict__ B, long sB,
                       u16* __restrict__ C, long sC,
                       const float* __restrict__ bias, int K) {
    __shared__ __align__(16) u16 As[2][128 * 64];
    __shared__ __align__(16) u16 Bs[2][128 * 64];
    const int z = blockIdx.z;
    const u16* Bb = B + (long)z * sB + (long)blockIdx.x * 128 * 512;

    const int tid = threadIdx.x;
    const int w = tid >> 6, lane = tid & 63;
    const int wy = w >> 1, wx = w & 1;
    const int quad = lane >> 4, mrow = lane & 15;

    long arow[4];
    #pragma unroll
    for (int j = 0; j < 4; ++j) arow[j] = (long)blockIdx.y * 128 + ((j * 256 + tid) >> 3);

    floatx4 acc[4][4];
    #pragma unroll
    for (int i = 0; i < 4; i++)
        #pragma unroll
        for (int j = 0; j < 4; j++)
            acc[i][j] = floatx4{0.f, 0.f, 0.f, 0.f};

    const int nk = K >> 6;
    stage64(A, 512, arow, Bb, 512, 0, tid, As[0], Bs[0]);
    for (int it = 0; it < nk; ++it) {
        const int cur = it & 1;
        __syncthreads();
        if (it + 1 < nk)
            stage64(A, 512, arow, Bb, 512, (it + 1) << 6, tid, As[1 - cur], Bs[1 - cur]);
        compute64(As[cur], Bs[cur], wy, wx, quad, mrow, acc);
    }

    const float* biasb = bias + (long)z * 512 + blockIdx.x * 128;
    if constexpr (TRANSC) {
        u16* Cb = C + (long)z * sC;
        #pragma unroll
        for (int ni = 0; ni < 4; ni++) {
            const int colt = wx * 64 + ni * 16 + mrow;
            const int n = blockIdx.x * 128 + colt;
            float bv = biasb[colt];
            #pragma unroll
            for (int mi = 0; mi < 4; mi++) {
                #pragma unroll
                for (int r = 0; r < 4; r++) {
                    const int m = blockIdx.y * 128 + wy * 64 + mi * 16 + quad * 4 + r;
                    float v = acc[mi][ni][r] + bv;
                    long addr = ((long)(((m >> 10) << 2) + (n >> 7)) * 128 + (n & 127)) * 1024 + (m & 1023);
                    Cb[addr] = f2bf_bits(v);
                }
            }
        }
    } else {
        u16* Cb = C + (long)z * sC + (long)blockIdx.y * 128 * 512 + blockIdx.x * 128;
        #pragma unroll
        for (int ni = 0; ni < 4; ni++) {
            const int col = wx * 64 + ni * 16 + mrow;
            float bv = biasb[col];
            #pragma unroll
            for (int mi = 0; mi < 4; mi++) {
                #pragma unroll
                for (int r = 0; r < 4; r++) {
                    const int row = wy * 64 + mi * 16 + quad * 4 + r;
                    Cb[(long)row * 512 + col] = f2bf_bits(acc[mi][ni][r] + bv);
                }
            }
        }
    }
}

// ---------------- scores: S[b][h][pslot][k] = Q[gather] @ K^T * isq, all experts ----------------
// grid x=8 (k-tiles), y=24 (packed tiles), z=16 (b*4+h)
__global__ __launch_bounds__(256)
void gemm_scores_kernel(const u16* __restrict__ Q, const u16* __restrict__ Km, u16* __restrict__ S,
                        const int* __restrict__ prix, const int* __restrict__ tmap,
                        const int* __restrict__ tt, float alpha) {
    const int b = blockIdx.z >> 2, h = blockIdx.z & 3;
    const int tile = blockIdx.y;
    if (tile >= tt[b]) return;
    const int e = tmap[b * 32 + tile];
    __shared__ __align__(16) u16 As[2][128 * 64];
    __shared__ __align__(16) u16 Bs[2][128 * 64];
    const u16* Abase = Q + (long)e * 4096 * 512 + h * 128;
    const u16* Bb = Km + ((long)e * 4096 + b * 1024 + blockIdx.x * 128) * 512 + h * 128;

    const int tid = threadIdx.x;
    const int w = tid >> 6, lane = tid & 63;
    const int wy = w >> 1, wx = w & 1;
    const int quad = lane >> 4, mrow = lane & 15;

    long arow[4];
    #pragma unroll
    for (int j = 0; j < 4; ++j)
        arow[j] = prix[b * 3072 + tile * 128 + ((j * 256 + tid) >> 3)];

    floatx4 acc[4][4];
    #pragma unroll
    for (int i = 0; i < 4; i++)
        #pragma unroll
        for (int j = 0; j < 4; j++)
            acc[i][j] = floatx4{0.f, 0.f, 0.f, 0.f};

    stage64(Abase, 512, arow, Bb, 512, 0, tid, As[0], Bs[0]);
    for (int it = 0; it < 2; ++it) {
        const int cur = it & 1;
        __syncthreads();
        if (it == 0)
            stage64(Abase, 512, arow, Bb, 512, 64, tid, As[1], Bs[1]);
        compute64(As[cur], Bs[cur], wy, wx, quad, mrow, acc);
    }

    u16* Cb = S + ((long)blockIdx.z * 3072 + tile * 128) * 1024 + blockIdx.x * 128;
    #pragma unroll
    for (int ni = 0; ni < 4; ni++) {
        const int col = wx * 64 + ni * 16 + mrow;
        #pragma unroll
        for (int mi = 0; mi < 4; mi++) {
            #pragma unroll
            for (int r = 0; r < 4; r++) {
                const int row = wy * 64 + mi * 16 + quad * 4 + r;
                Cb[(long)row * 1024 + col] = f2bf_bits(acc[mi][ni][r] * alpha);
            }
        }
    }
}

// ---------------- PV: OC[packed] = softmax(S) @ VT, all experts ----------------
// grid x=1, y=24, z=16
__global__ __launch_bounds__(256)
void gemm_pv_kernel(const u16* __restrict__ S, const u16* __restrict__ VT, u16* __restrict__ OC,
                    const int* __restrict__ tmap, const int* __restrict__ tt) {
    const int b = blockIdx.z >> 2, h = blockIdx.z & 3;
    const int tile = blockIdx.y;
    if (tile >= tt[b]) return;
    const int e = tmap[b * 32 + tile];
    __shared__ __align__(16) u16 As[2][128 * 64];
    __shared__ __align__(16) u16 Bs[2][128 * 64];
    const u16* Abase = S + ((long)blockIdx.z * 3072 + tile * 128) * 1024;
    const u16* Bb = VT + ((long)e * 16 + blockIdx.z) * 131072;

    const int tid = threadIdx.x;
    const int w = tid >> 6, lane = tid & 63;
    const int wy = w >> 1, wx = w & 1;
    const int quad = lane >> 4, mrow = lane & 15;

    long arow[4];
    #pragma unroll
    for (int j = 0; j < 4; ++j) arow[j] = (j * 256 + tid) >> 3;

    floatx4 acc[4][4];
    #pragma unroll
    for (int i = 0; i < 4; i++)
        #pragma unroll
        for (int j = 0; j < 4; j++)
            acc[i][j] = floatx4{0.f, 0.f, 0.f, 0.f};

    stage64(Abase, 1024, arow, Bb, 1024, 0, tid, As[0], Bs[0]);
    for (int it = 0; it < 16; ++it) {
        const int cur = it & 1;
        __syncthreads();
        if (it + 1 < 16)
            stage64(Abase, 1024, arow, Bb, 1024, (it + 1) << 6, tid, As[1 - cur], Bs[1 - cur]);
        compute64(As[cur], Bs[cur], wy, wx, quad, mrow, acc);
    }

    u16* Cb = OC + ((long)b * 3072 + tile * 128) * 512 + h * 128;
    #pragma unroll
    for (int ni = 0; ni < 4; ni++) {
        const int col = wx * 64 + ni * 16 + mrow;
        #pragma unroll
        for (int mi = 0; mi < 4; mi++) {
            #pragma unroll
            for (int r = 0; r < 4; r++) {
                const int row = wy * 64 + mi * 16 + quad * 4 + r;
                Cb[(long)row * 512 + col] = f2bf_bits(acc[mi][ni][r]);
            }
        }
    }
}

// ---------------- packed GEMM (Wo / FFN1 / FFN2): per-tile expert weights ----------------
// grid x = N/128, y = 96 (b = y/24, tile = y%24)
template<bool RELU>
__global__ __launch_bounds__(256)
void gemm_packed_kernel(const u16* __restrict__ A, int lda,
                        const u16* __restrict__ B, int ldb, long sBe,
                        u16* __restrict__ C, int ldc,
                        const float* __restrict__ bias, long sBiasE,
                        const int* __restrict__ tmap, const int* __restrict__ tt, int K) {
    const int b = blockIdx.y / 24, tile = blockIdx.y % 24;
    if (tile >= tt[b]) return;
    const int e = tmap[b * 32 + tile];
    __shared__ __align__(16) u16 As[2][128 * 64];
    __shared__ __align__(16) u16 Bs[2][128 * 64];
    const long rbase = (long)b * 3072 + tile * 128;
    const u16* Ab = A + rbase * lda;
    const u16* Bb = B + (long)e * sBe + (long)blockIdx.x * 128 * ldb;

    const int tid = threadIdx.x;
    const int w = tid >> 6, lane = tid & 63;
    const int wy = w >> 1, wx = w & 1;
    const int quad = lane >> 4, mrow = lane & 15;

    long arow[4];
    #pragma unroll
    for (int j = 0; j < 4; ++j) arow[j] = (j * 256 + tid) >> 3;

    floatx4 acc[4][4];
    #pragma unroll
    for (int i = 0; i < 4; i++)
        #pragma unroll
        for (int j = 0; j < 4; j++)
            acc[i][j] = floatx4{0.f, 0.f, 0.f, 0.f};

    const int nk = K >> 6;
    stage64(Ab, lda, arow, Bb, ldb, 0, tid, As[0], Bs[0]);
    for (int it = 0; it < nk; ++it) {
        const int cur = it & 1;
        __syncthreads();
        if (it + 1 < nk)
            stage64(Ab, lda, arow, Bb, ldb, (it + 1) << 6, tid, As[1 - cur], Bs[1 - cur]);
        compute64(As[cur], Bs[cur], wy, wx, quad, mrow, acc);
    }

    u16* Cb = C + rbase * ldc + (long)blockIdx.x * 128;
    const float* biasb = bias + (long)e * sBiasE + blockIdx.x * 128;
    #pragma unroll
    for (int ni = 0; ni < 4; ni++) {
        const int col = wx * 64 + ni * 16 + mrow;
        float bv = biasb[col];
        #pragma unroll
        for (int mi = 0; mi < 4; mi++) {
            #pragma unroll
            for (int r = 0; r < 4; r++) {
                const int row = wy * 64 + mi * 16 + quad * 4 + r;
                float v = acc[mi][ni][r] + bv;
                if (RELU) v = fmaxf(v, 0.f);
                Cb[(long)row * ldc + col] = f2bf_bits(v);
            }
        }
    }
}

// ---------------- softmax over packed S rows ----------------
// grid 49152 = (b*4+h)*3072 + pslot
__global__ __launch_bounds__(256)
void softmax_kernel(u16* __restrict__ S, const int* __restrict__ act, const int* __restrict__ pt) {
    int blk = blockIdx.x;
    int pslot = blk % 3072;
    int bh = blk / 3072;
    int b = bh >> 2;
    if (pslot >= pt[b] || !act[b * 3072 + pslot]) return;
    u16* p = S + ((long)bh * 3072 + pslot) * 1024;
    int t = threadIdx.x, w = t >> 6, lane = t & 63;
    float v[4];
    float mx = -1e30f;
    #pragma unroll
    for (int i = 0; i < 4; i++) {
        v[i] = bf_bits2f(p[t + 256 * i]);
        mx = fmaxf(mx, v[i]);
    }
    #pragma unroll
    for (int o = 32; o; o >>= 1) mx = fmaxf(mx, __shfl_down(mx, o, 64));
    __shared__ float red[8];
    if (lane == 0) red[w] = mx;
    __syncthreads();
    mx = fmaxf(fmaxf(red[0], red[1]), fmaxf(red[2], red[3]));
    float sum = 0.f;
    #pragma unroll
    for (int i = 0; i < 4; i++) { v[i] = __expf(v[i] - mx); sum += v[i]; }
    #pragma unroll
    for (int o = 32; o; o >>= 1) sum += __shfl_down(sum, o, 64);
    if (lane == 0) red[4 + w] = sum;
    __syncthreads();
    float inv = 1.f / (red[4] + red[5] + red[6] + red[7]);
    #pragma unroll
    for (int i = 0; i < 4; i++) p[t + 256 * i] = f2bf_bits(v[i] * inv);
}

// ---------------- LN1 on packed rows ----------------
// grid 12288 = b*3072 + pslot, 128 threads
__global__ __launch_bounds__(128)
void ln1_kernel(const float* __restrict__ x, const u16* __restrict__ tc,
                const int* __restrict__ prix, const int* __restrict__ act,
                const int* __restrict__ tmap, const int* __restrict__ pt,
                const float* __restrict__ s_all, const float* __restrict__ b_all,
                u16* __restrict__ hb) {
    int blk = blockIdx.x;
    int b = blk / 3072, pslot = blk % 3072;
    if (pslot >= pt[b]) return;
    long row = (long)b * 3072 + pslot;
    int tid = threadIdx.x, w = tid >> 6, lane = tid & 63;
    if (!act[row]) {
        *(ushort4*)(hb + row * 512 + tid * 4) = make_ushort4(0, 0, 0, 0);
        return;
    }
    int r = prix[row];
    int e = tmap[b * 32 + (pslot >> 7)];
    float4 xv = *(const float4*)(x + (long)r * 512 + tid * 4);
    ushort4 tu = *(const ushort4*)(tc + row * 512 + tid * 4);
    float v[4] = {xv.x + bf_bits2f(tu.x), xv.y + bf_bits2f(tu.y),
                  xv.z + bf_bits2f(tu.z), xv.w + bf_bits2f(tu.w)};
    float sum = v[0] + v[1] + v[2] + v[3];
    #pragma unroll
    for (int o = 32; o; o >>= 1) sum += __shfl_down(sum, o, 64);
    __shared__ float sh[4];
    if (lane == 0) sh[w] = sum;
    __syncthreads();
    float mu = (sh[0] + sh[1]) * (1.f / 512.f);
    float sq = 0.f;
    #pragma unroll
    for (int j = 0; j < 4; j++) { float d = v[j] - mu; sq += d * d; }
    #pragma unroll
    for (int o = 32; o; o >>= 1) sq += __shfl_down(sq, o, 64);
    if (lane == 0) sh[2 + w] = sq;
    __syncthreads();
    float inv = 1.f / sqrtf((sh[2] + sh[3]) * (1.f / 512.f) + 1e-5f);
    float4 sv = *(const float4*)(s_all + e * 512 + tid * 4);
    float4 bv = *(const float4*)(b_all + e * 512 + tid * 4);
    ushort4 ub;
    ub.x = f2bf_bits((v[0] - mu) * inv * sv.x + bv.x);
    ub.y = f2bf_bits((v[1] - mu) * inv * sv.y + bv.y);
    ub.z = f2bf_bits((v[2] - mu) * inv * sv.z + bv.z);
    ub.w = f2bf_bits((v[3] - mu) * inv * sv.w + bv.w);
    *(ushort4*)(hb + row * 512 + tid * 4) = ub;
}

// ---------------- LN2 + weighted accumulate over all 8 experts ----------------
__global__ __launch_bounds__(128)
void ln2acc_kernel(const u16* __restrict__ hb, const u16* __restrict__ t2,
                   const float* __restrict__ s_all, const float* __restrict__ b_all,
                   const float* __restrict__ rw, const int* __restrict__ smap,
                   float* __restrict__ out) {
    long r = blockIdx.x;
    int b = (int)(r >> 10);
    int tid = threadIdx.x, w = tid >> 6, lane = tid & 63;
    __shared__ float sh[4];
    float4 acc = make_float4(0.f, 0.f, 0.f, 0.f);
    for (int e = 0; e < 8; e++) {
        int ps = smap[r * 8 + e];
        if (ps >= 0) {   // block-uniform
            float wgt = rw[r * 8 + e];
            long row = (long)b * 3072 + ps;
            ushort4 hu = *(const ushort4*)(hb + row * 512 + tid * 4);
            ushort4 fu = *(const ushort4*)(t2 + row * 512 + tid * 4);
            float v[4] = {bf_bits2f(hu.x) + bf_bits2f(fu.x), bf_bits2f(hu.y) + bf_bits2f(fu.y),
                          bf_bits2f(hu.z) + bf_bits2f(fu.z), bf_bits2f(hu.w) + bf_bits2f(fu.w)};
            float sum = v[0] + v[1] + v[2] + v[3];
            #pragma unroll
            for (int o = 32; o; o >>= 1) sum += __shfl_down(sum, o, 64);
            if (lane == 0) sh[w] = sum;
            __syncthreads();
            float mu = (sh[0] + sh[1]) * (1.f / 512.f);
            float sq = 0.f;
            #pragma unroll
            for (int j = 0; j < 4; j++) { float d = v[j] - mu; sq += d * d; }
            #pragma unroll
            for (int o = 32; o; o >>= 1) sq += __shfl_down(sq, o, 64);
            if (lane == 0) sh[2 + w] = sq;
            __syncthreads();
            float inv = 1.f / sqrtf((sh[2] + sh[3]) * (1.f / 512.f) + 1e-5f);
            float4 sv = *(const float4*)(s_all + e * 512 + tid * 4);
            float4 bv = *(const float4*)(b_all + e * 512 + tid * 4);
            acc.x += wgt * ((v[0] - mu) * inv * sv.x + bv.x);
            acc.y += wgt * ((v[1] - mu) * inv * sv.y + bv.y);
            acc.z += wgt * ((v[2] - mu) * inv * sv.z + bv.z);
            acc.w += wgt * ((v[3] - mu) * inv * sv.w + bv.w);
            __syncthreads();
        }
    }
    *(float4*)(out + r * 512 + tid * 4) = acc;
}

// ---------------- workspace layout (bytes), ws_size = 256 MiB (measured R6 fill) ----------------
static const size_t WB_B   = 0;           // 48 MiB: wq,wk,wv,wo (8x262144 each), w1 (8x1048576), w2 (8x1048576)
static const size_t RW_B   = 50331648;    // f32 [4096][8]
static const size_t PB_B   = 50462720;    // f32 [3][8][512]
static const size_t TT_B   = 50511872;    // i32[4] tiles per b
static const size_t PT_B   = 50511888;    // i32[4] packed rows per b
static const size_t TMAP_B = 50511904;    // i32 [4][32]
static const size_t PRIX_B = 50512416;    // i32 [4][3072]
static const size_t ACT_B  = 50561568;    // i32 [4][3072]
static const size_t SMAP_B = 50610720;    // i32 [4096][8]
static const size_t XB_B   = 50741792;    // bf16 [4096][512]
static const size_t Q8_B   = 54936096;    // bf16 [8][4096][512] (32 MiB)
static const size_t K8_B   = 88490528;    // bf16 [8][4096][512] (32 MiB)
static const size_t VT_B   = 122044960;   // bf16 [8][16][128][1024] (32 MiB)
static const size_t S_B    = 155599392;   // bf16 [16][3072][1024] (96 MiB), end 256,262,688 < 268,435,456
static const size_t OC_B   = Q8_B;        // bf16 [4][3072][512] (12.6 MB) — Q dead after scores
static const size_t TC_B   = K8_B;        // bf16 [4][3072][512] — K dead after scores
static const size_t HB_B   = Q8_B;        // LN1 out — OC dead after Wo
static const size_t MID_B  = S_B;         // bf16 [4][3072][2048] (50 MB) — S dead after PV
static const size_t T2_B   = VT_B;        // bf16 [4][3072][512] — VT dead after PV

extern "C" void kernel_launch(void* const* d_in, const int* in_sizes, int n_in,
                              void* d_out, int out_size, void* d_ws, size_t ws_size,
                              hipStream_t stream) {
    const float* x      = (const float*)d_in[0];
    const float* gate_w = (const float*)d_in[1];
    const float* gate_b = (const float*)d_in[2];
    const float* ln1_s  = (const float*)d_in[3];
    const float* ln1_b  = (const float*)d_in[4];
    const float* ln2_s  = (const float*)d_in[5];
    const float* ln2_b  = (const float*)d_in[6];
    const float* wq = (const float*)d_in[7];
    const float* wk = (const float*)d_in[8];
    const float* wv = (const float*)d_in[9];
    const float* wo = (const float*)d_in[10];
    const float* bo = (const float*)d_in[14];
    const float* w1 = (const float*)d_in[15];
    const float* b1 = (const float*)d_in[16];
    const float* w2 = (const float*)d_in[17];
    const float* b2 = (const float*)d_in[18];
    float* out = (float*)d_out;

    char* ws = (char*)d_ws;
    u16*   WB   = (u16*)(ws + WB_B);
    float* RW   = (float*)(ws + RW_B);
    float* PB   = (float*)(ws + PB_B);
    int*   TT   = (int*)(ws + TT_B);
    int*   PT   = (int*)(ws + PT_B);
    int*   TMAP = (int*)(ws + TMAP_B);
    int*   PRIX = (int*)(ws + PRIX_B);
    int*   ACT  = (int*)(ws + ACT_B);
    int*   SMAP = (int*)(ws + SMAP_B);
    u16*   XB   = (u16*)(ws + XB_B);
    u16*   Q8   = (u16*)(ws + Q8_B);     // also the QK contiguous base (K8 right after)
    u16*   VT8  = (u16*)(ws + VT_B);
    u16*   S    = (u16*)(ws + S_B);
    u16*   K8   = (u16*)(ws + K8_B);
    u16*   OC   = (u16*)(ws + OC_B);
    u16*   TC   = (u16*)(ws + TC_B);
    u16*   HB   = (u16*)(ws + HB_B);
    u16*   MID  = (u16*)(ws + MID_B);
    u16*   T2   = (u16*)(ws + T2_B);

    // ---- setup ----
    cast_bf16_kernel<<<dim3(2048), 256, 0, stream>>>(x, XB, 4096 * 512 / 4);
    transpose_cast_kernel<<<dim3(16,16,8), dim3(32,8), 0, stream>>>(wq, WB + 0,        512,  512,  262144,  262144);
    transpose_cast_kernel<<<dim3(16,16,8), dim3(32,8), 0, stream>>>(wk, WB + 2097152,  512,  512,  262144,  262144);
    transpose_cast_kernel<<<dim3(16,16,8), dim3(32,8), 0, stream>>>(wv, WB + 4194304,  512,  512,  262144,  262144);
    transpose_cast_kernel<<<dim3(16,16,8), dim3(32,8), 0, stream>>>(wo, WB + 6291456,  512,  512,  262144,  262144);
    transpose_cast_kernel<<<dim3(64,16,8), dim3(32,8), 0, stream>>>(w1, WB + 8388608,  512,  2048, 1048576, 1048576);
    transpose_cast_kernel<<<dim3(16,64,8), dim3(32,8), 0, stream>>>(w2, WB + 16777216, 2048, 512,  1048576, 1048576);
    pack_bias_kernel<<<dim3(16,3), 256, 0, stream>>>((const float*)d_in[11], (const float*)d_in[12],
                                                     (const float*)d_in[13], PB);
    router_kernel<<<4096, 512, 0, stream>>>(x, gate_w, gate_b, RW, out + 2097152);
    build_lists_kernel<<<4, 256, 0, stream>>>(RW, PRIX, ACT, SMAP, TMAP, TT, PT);

    const float isq = 0.08838834764831845f;  // 1/sqrt(128)

    // ---- Q,K for all 8 experts (z=0..7 Q, 8..15 K), one launch ----
    gemm_dense_kernel<false><<<dim3(4,32,16), 256, 0, stream>>>(
        XB, WB, 262144, Q8, 2097152, PB, 512);
    // ---- V for all 8 experts, direct-transposed into VT ----
    gemm_dense_kernel<true><<<dim3(4,32,8), 256, 0, stream>>>(
        XB, WB + 4194304, 262144, VT8, 2097152, PB + 8192, 512);

    // ---- scores (all experts, packed) ----
    gemm_scores_kernel<<<dim3(8,24,16), 256, 0, stream>>>(
        Q8, K8, S, PRIX, TMAP, TT, isq);
    // ---- softmax ----
    softmax_kernel<<<49152, 256, 0, stream>>>(S, ACT, PT);
    // ---- PV ----
    gemm_pv_kernel<<<dim3(1,24,16), 256, 0, stream>>>(S, VT8, OC, TMAP, TT);

    // ---- Wo ----
    gemm_packed_kernel<false><<<dim3(4,96), 256, 0, stream>>>(
        OC, 512, WB + 6291456, 512, 262144, TC, 512, bo, 512, TMAP, TT, 512);
    // ---- LN1 ----
    ln1_kernel<<<12288, 128, 0, stream>>>(x, TC, PRIX, ACT, TMAP, PT, ln1_s, ln1_b, HB);
    // ---- FFN1 ----
    gemm_packed_kernel<true><<<dim3(16,96), 256, 0, stream>>>(
        HB, 512, WB + 8388608, 512, 1048576, MID, 2048, b1, 2048, TMAP, TT, 512);
    // ---- FFN2 ----
    gemm_packed_kernel<false><<<dim3(4,96), 256, 0, stream>>>(
        MID, 2048, WB + 16777216, 2048, 1048576, T2, 512, b2, 512, TMAP, TT, 2048);
    // ---- LN2 + routing-weighted accumulate ----
    ln2acc_kernel<<<4096, 128, 0, stream>>>(HB, T2, ln2_s, ln2_b, RW, SMAP, out);
}